// Round 4
// baseline (126.841 us; speedup 1.0000x reference)
//
#include <hip/hip_runtime.h>

#define EPSF 1e-6f

typedef __bf16 bf16x8 __attribute__((ext_vector_type(8)));
typedef float f32x4 __attribute__((ext_vector_type(4)));
typedef __attribute__((address_space(3))) unsigned int as3_uint;
typedef __attribute__((address_space(1))) const unsigned int as1_uint;

__device__ __forceinline__ unsigned short f2bf(float f) {
  unsigned int u = __builtin_bit_cast(unsigned int, f);
  u += 0x7fffu + ((u >> 16) & 1u);
  return (unsigned short)(u >> 16);
}
__device__ __forceinline__ float bf2f(unsigned short u) {
  unsigned int v = (unsigned int)u << 16;
  return __builtin_bit_cast(float, v);
}

// ---------------- log_map at origin: x [2048,1024] -> v (bf16) ----------------
__global__ __launch_bounds__(256) void prep_logmap(
    const float* __restrict__ x, unsigned short* __restrict__ vbf) {
  int row = blockIdx.x;
  int tid = threadIdx.x;
  const float* xr = x + (size_t)row * 1024;
  float vals[4];
  float ssq = 0.f;
#pragma unroll
  for (int i = 0; i < 4; ++i) {
    int c = tid + i * 256;
    float t = xr[c];
    if (c == 0) {
      vals[i] = 0.f;
    } else {
      t = fminf(fmaxf(t, -8.f), 8.f);
      vals[i] = t;
      ssq += t * t;
    }
  }
#pragma unroll
  for (int off = 32; off; off >>= 1) ssq += __shfl_xor(ssq, off);
  __shared__ float red[4];
  int wv = tid >> 6;
  if ((tid & 63) == 0) red[wv] = ssq;
  __syncthreads();
  ssq = red[0] + red[1] + red[2] + red[3];

  float y0 = sqrtf(1.f + ssq + EPSF);
  float xy = fminf(-y0, -(1.f + EPSF));
  float mxy = fmaxf(-xy, 1.f + EPSF);
  float dd = fmaxf(acoshf(mxy), 0.001f);
  float d0 = y0 + xy;
  float inn = ssq - d0 * d0;
  float dn = sqrtf(fmaxf(inn, EPSF));
  float inv = dd / (dn + EPSF);

  unsigned short* vr = vbf + (size_t)row * 1024;
#pragma unroll
  for (int i = 0; i < 4; ++i) {
    int c = tid + i * 256;
    float o = (c == 0) ? d0 * inv : vals[i] * inv;
    vr[c] = f2bf(o);
  }
}

// ---------------- all 4 weights f32 -> bf16, one dispatch ----------------
__global__ __launch_bounds__(256) void conv_weights(
    const float* __restrict__ Wq, const float* __restrict__ Wk,
    const float* __restrict__ Wv, const float* __restrict__ Wo,
    unsigned short* __restrict__ wqk, unsigned short* __restrict__ wvb,
    unsigned short* __restrict__ wob) {
  int y = blockIdx.y;
  const float* src = (y == 0) ? Wq : (y == 1) ? Wk : (y == 2) ? Wv : Wo;
  unsigned short* dst = (y == 0) ? wqk : (y == 1) ? wqk + 1048576
                        : (y == 2) ? wvb : wob;
  int i = blockIdx.x * 256 + threadIdx.x;
  f32x4 v = ((const f32x4*)src)[i];
  ushort4 o;
  o.x = f2bf(v[0]); o.y = f2bf(v[1]); o.z = f2bf(v[2]); o.w = f2bf(v[3]);
  ((ushort4*)dst)[i] = o;
}

// ---------------- shared GEMM body: C[row0.., col0..] (BM=128 BN=64 BK=64) ----------------
__device__ __forceinline__ void gemm_body(
    const unsigned short* __restrict__ A, const unsigned short* __restrict__ Bw,
    unsigned short* __restrict__ C, int N, int K, int row0, int col0,
    unsigned short* As, unsigned short* Bs) {
  int tid = threadIdx.x;
  int lane = tid & 63, w = tid >> 6;
  int wm = (w & 1) * 64, wn = (w >> 1) * 32;
  int lq = lane & 15, g = lane >> 4;
  f32x4 acc[4][2] = {};

  const unsigned short* Ag =
      A + (size_t)(row0 + w * 8 + (lane >> 3)) * K + (lane & 7) * 8;
  const unsigned short* Bg =
      Bw + (size_t)(col0 + w * 8 + (lane >> 3)) * K + (lane & 7) * 8;

  for (int k0 = 0; k0 < K; k0 += 64) {
    __syncthreads();
#pragma unroll
    for (int it = 0; it < 4; ++it)
      __builtin_amdgcn_global_load_lds(
          (as1_uint*)(Ag + (size_t)(it * 32) * K + k0),
          (as3_uint*)&As[(it * 32 + w * 8) * 64], 16, 0, 0);
#pragma unroll
    for (int it = 0; it < 2; ++it)
      __builtin_amdgcn_global_load_lds(
          (as1_uint*)(Bg + (size_t)(it * 32) * K + k0),
          (as3_uint*)&Bs[(it * 32 + w * 8) * 64], 16, 0, 0);
    __syncthreads();
#pragma unroll
    for (int ks = 0; ks < 2; ++ks) {
      bf16x8 af[4], bfr[2];
#pragma unroll
      for (int i = 0; i < 4; ++i)
        af[i] = *(const bf16x8*)&As[(wm + i * 16 + lq) * 64 + ks * 32 + g * 8];
#pragma unroll
      for (int j = 0; j < 2; ++j)
        bfr[j] = *(const bf16x8*)&Bs[(wn + j * 16 + lq) * 64 + ks * 32 + g * 8];
#pragma unroll
      for (int i = 0; i < 4; ++i)
#pragma unroll
        for (int j = 0; j < 2; ++j)
          acc[i][j] =
              __builtin_amdgcn_mfma_f32_16x16x32_bf16(af[i], bfr[j], acc[i][j], 0, 0, 0);
    }
  }
#pragma unroll
  for (int i = 0; i < 4; ++i)
#pragma unroll
    for (int j = 0; j < 2; ++j)
#pragma unroll
      for (int r = 0; r < 4; ++r)
        C[(size_t)(row0 + wm + i * 16 + g * 4 + r) * N + col0 + wn + j * 16 + lq] =
            f2bf(acc[i][j][r]);
}

// QK gemm (blocks 0..511) + Vt gemm (blocks 512..767) fused in one dispatch.
__global__ __launch_bounds__(256) void gemm_fused(
    const unsigned short* __restrict__ vbf, const unsigned short* __restrict__ wqk,
    const unsigned short* __restrict__ wvb, unsigned short* __restrict__ qkb,
    unsigned short* __restrict__ vtb) {
  __shared__ unsigned short As[128 * 64];
  __shared__ unsigned short Bs[64 * 64];
  int bid = blockIdx.x;
  if (bid < 512) {
    gemm_body(vbf, wqk, qkb, 2048, 1024, (bid & 15) * 128, (bid >> 4) * 64, As, Bs);
  } else {
    int t = bid - 512;
    gemm_body(wvb, vbf, vtb, 2048, 1024, (t & 7) * 128, (t >> 3) * 64, As, Bs);
  }
}

// Wo gemm: [2048,1024] @ Wo^T -> [2048,1024]
__global__ __launch_bounds__(256) void gemm_wo(
    const unsigned short* __restrict__ A, const unsigned short* __restrict__ Bw,
    unsigned short* __restrict__ C) {
  __shared__ unsigned short As[128 * 64];
  __shared__ unsigned short Bs[64 * 64];
  gemm_body(A, Bw, C, 1024, 1024, (blockIdx.x & 15) * 128, (blockIdx.x >> 4) * 64,
            As, Bs);
}

// ---------------- per-head projection for q AND k in one dispatch ----------------
__global__ __launch_bounds__(256) void proj_both(
    const unsigned short* __restrict__ qkb, unsigned short* __restrict__ qb,
    unsigned short* __restrict__ kb) {
  int tid = threadIdx.x;
  int qmode = (blockIdx.y == 0);
  int g = blockIdx.x * 4 + (tid >> 6);
  int lane = tid & 63;
  int row = g >> 4, head = g & 15;
  const unsigned short* src = qkb + (qmode ? 0 : 1024);
  unsigned short* dst = qmode ? qb : kb;
  float t = bf2f(src[(size_t)row * 2048 + head * 64 + lane]);
  float sp = fminf(fmaxf(t, -5.f), 5.f);
  float ssq = (lane == 0) ? 0.f : sp * sp;
#pragma unroll
  for (int o = 32; o; o >>= 1) ssq += __shfl_xor(ssq, o);
  float x0 = sqrtf(1.f + ssq + EPSF);
  float o = (lane == 0) ? (qmode ? -x0 : x0) : sp;
  if (qmode) o *= 0.125f;
  dst[(size_t)row * 1024 + head * 64 + lane] = f2bf(o);
}

// ---------------- MFMA flash attention, KVBLK=128, T14 async-stage, XCD swizzle ----
__global__ __launch_bounds__(256) void attn_mfma(
    const unsigned short* __restrict__ Qb, const unsigned short* __restrict__ Kb,
    const unsigned short* __restrict__ Vtb, unsigned short* __restrict__ Obf) {
  __shared__ unsigned short Ks[128 * 64];
  __shared__ unsigned short Vs[64 * 128];
  __shared__ unsigned short Ps[4 * 16 * 128];
  int tid = threadIdx.x;
  int lane = tid & 63, w = tid >> 6;
  int g = lane >> 4, lq = lane & 15;
  // XCD grouping: all 16 q-tiles of one (b,h) on one XCD
  int j = blockIdx.x;
  int bh = (j & 7) + 8 * (j >> 7);
  int qt = (j >> 3) & 15;
  int b = bh >> 4, h = bh & 15;

  const unsigned short* qrow =
      Qb + (size_t)(b * 1024 + qt * 64 + w * 16 + lq) * 1024 + h * 64;
  bf16x8 qf0 = *(const bf16x8*)(qrow + g * 8);
  bf16x8 qf1 = *(const bf16x8*)(qrow + 32 + g * 8);

  float mreg = -1e30f, lreg = 0.f;
  f32x4 acc[4] = {};
  unsigned short* Pw = Ps + w * 16 * 128;
  int sx = 8 * (lq & 7);

  const unsigned short* Ksrc = Kb + (size_t)(b * 1024) * 1024 + h * 64;
  const unsigned short* Vsrc = Vtb + (size_t)(h * 64) * 2048 + b * 1024;

  // staging geometry
  int skr = tid >> 3, skc = tid & 7;              // K: rows skr+32it, col grp skc
  int kw = skr * 64 + 8 * (skc ^ (skr & 7));
  const unsigned short* Kp = Ksrc + (size_t)skr * 1024 + skc * 8;
  int svr = tid >> 4, svc = tid & 15;             // V: rows svr+16it, col grp svc
  int vw = svr * 128 + (svc >> 3) * 64 + 8 * ((svc & 7) ^ (svr & 7));
  const unsigned short* Vp = Vsrc + (size_t)svr * 2048 + svc * 8;

  uint4 kA[4], vA[4], kB[4], vB[4];
  auto loadA = [&](int kt) {
#pragma unroll
    for (int it = 0; it < 4; ++it) {
      kA[it] = *(const uint4*)(Kp + (size_t)(kt * 128 + it * 32) * 1024);
      vA[it] = *(const uint4*)(Vp + (size_t)(it * 16) * 2048 + kt * 128);
    }
  };
  auto loadB = [&](int kt) {
#pragma unroll
    for (int it = 0; it < 4; ++it) {
      kB[it] = *(const uint4*)(Kp + (size_t)(kt * 128 + it * 32) * 1024);
      vB[it] = *(const uint4*)(Vp + (size_t)(it * 16) * 2048 + kt * 128);
    }
  };
  auto writeLDS = [&](uint4* kk, uint4* vv) {
#pragma unroll
    for (int it = 0; it < 4; ++it) {
      *(uint4*)&Ks[kw + it * 32 * 64] = kk[it];
      *(uint4*)&Vs[vw + it * 16 * 128] = vv[it];
    }
  };
  auto compute = [&]() {
    f32x4 st[8];
#pragma unroll
    for (int i = 0; i < 8; ++i) {
      int ro = i * 16 + lq;
      int rb = ro * 64, xx = 8 * (ro & 7);
      bf16x8 a0 = *(const bf16x8*)&Ks[rb + ((g * 8) ^ xx)];
      bf16x8 a1 = *(const bf16x8*)&Ks[rb + ((32 + g * 8) ^ xx)];
      f32x4 z = {};
      z = __builtin_amdgcn_mfma_f32_16x16x32_bf16(a0, qf0, z, 0, 0, 0);
      st[i] = __builtin_amdgcn_mfma_f32_16x16x32_bf16(a1, qf1, z, 0, 0, 0);
    }
    float pmax = st[0][0];
#pragma unroll
    for (int i = 0; i < 8; ++i)
#pragma unroll
      for (int r = 0; r < 4; ++r) pmax = fmaxf(pmax, st[i][r]);
    pmax = fmaxf(pmax, __shfl_xor(pmax, 16));
    pmax = fmaxf(pmax, __shfl_xor(pmax, 32));
    float nm = fmaxf(mreg, pmax);
    float sc_ = __expf(mreg - nm);
    mreg = nm;
    float ps = 0.f;
#pragma unroll
    for (int i = 0; i < 8; ++i) {
      ushort4 pq;
      float p0 = __expf(st[i][0] - nm);
      float p1 = __expf(st[i][1] - nm);
      float p2 = __expf(st[i][2] - nm);
      float p3 = __expf(st[i][3] - nm);
      ps += (p0 + p1) + (p2 + p3);
      pq.x = f2bf(p0); pq.y = f2bf(p1); pq.z = f2bf(p2); pq.w = f2bf(p3);
      *(ushort4*)&Pw[lq * 128 + ((g * 4 + i * 16) ^ sx)] = pq;
    }
    ps += __shfl_xor(ps, 16);
    ps += __shfl_xor(ps, 32);
    lreg = lreg * sc_ + ps;

    float scr[4];
#pragma unroll
    for (int r = 0; r < 4; ++r) scr[r] = __shfl(sc_, g * 4 + r);
#pragma unroll
    for (int jj = 0; jj < 4; ++jj)
#pragma unroll
      for (int r = 0; r < 4; ++r) acc[jj][r] *= scr[r];
#pragma unroll
    for (int ks = 0; ks < 4; ++ks) {
      bf16x8 pa = *(const bf16x8*)&Pw[lq * 128 + ((ks * 32 + g * 8) ^ sx)];
#pragma unroll
      for (int jj = 0; jj < 4; ++jj) {
        int vr = 16 * jj + lq;
        bf16x8 vb = *(const bf16x8*)&Vs[vr * 128 + (ks >> 1) * 64 +
                                        (((ks & 1) * 32 + g * 8) ^ (8 * (vr & 7)))];
        acc[jj] = __builtin_amdgcn_mfma_f32_16x16x32_bf16(pa, vb, acc[jj], 0, 0, 0);
      }
    }
  };

  loadA(0);
  for (int kt = 0; kt < 8; kt += 2) {
    __syncthreads();
    writeLDS(kA, vA);
    loadB(kt + 1);
    __syncthreads();
    compute();
    __syncthreads();
    writeLDS(kB, vB);
    if (kt + 2 < 8) loadA(kt + 2);
    __syncthreads();
    compute();
  }

  float linv = 1.f / lreg;
  float ilr[4];
#pragma unroll
  for (int r = 0; r < 4; ++r) ilr[r] = __shfl(linv, g * 4 + r);
  unsigned short* obase =
      Obf + (size_t)(b * 1024 + qt * 64 + w * 16) * 1024 + h * 64;
#pragma unroll
  for (int r = 0; r < 4; ++r)
#pragma unroll
    for (int jj = 0; jj < 4; ++jj)
      obase[(size_t)(g * 4 + r) * 1024 + 16 * jj + lq] = f2bf(acc[jj][r] * ilr[r]);
}

// ---------------- exp_map at origin + project (bf16 in, f32 out) ----------------
__global__ __launch_bounds__(256) void expmap_project(
    const unsigned short* __restrict__ c2, float* __restrict__ out) {
  int row = blockIdx.x;
  int tid = threadIdx.x;
  const unsigned short* cr = c2 + (size_t)row * 1024;
  float vals[4];
  float ssq = 0.f;
#pragma unroll
  for (int i = 0; i < 4; ++i) {
    int c = tid + i * 256;
    float t = bf2f(cr[c]);
    vals[i] = (c == 0) ? 0.f : t;
    ssq += vals[i] * vals[i];
  }
#pragma unroll
  for (int off = 32; off; off >>= 1) ssq += __shfl_xor(ssq, off);
  __shared__ float red1[4], red2[4];
  int wv = tid >> 6;
  if ((tid & 63) == 0) red1[wv] = ssq;
  __syncthreads();
  ssq = red1[0] + red1[1] + red1[2] + red1[3];
  float vn = fminf(sqrtf(ssq + EPSF), 5.f);
  float bf = sinhf(vn) / (vn + EPSF);
  float s2 = 0.f;
#pragma unroll
  for (int i = 0; i < 4; ++i) {
    float r = fminf(fmaxf(bf * vals[i], -8.f), 8.f);
    vals[i] = r;
    s2 += r * r;
  }
#pragma unroll
  for (int off = 32; off; off >>= 1) s2 += __shfl_xor(s2, off);
  if ((tid & 63) == 0) red2[wv] = s2;
  __syncthreads();
  s2 = red2[0] + red2[1] + red2[2] + red2[3];
  float x0 = sqrtf(1.f + s2 + EPSF);
  float* orow = out + (size_t)row * 1024;
#pragma unroll
  for (int i = 0; i < 4; ++i) {
    int c = tid + i * 256;
    orow[c] = (c == 0) ? x0 : vals[i];
  }
}

extern "C" void kernel_launch(void* const* d_in, const int* in_sizes, int n_in,
                              void* d_out, int out_size, void* d_ws, size_t ws_size,
                              hipStream_t stream) {
  (void)in_sizes; (void)n_in; (void)out_size; (void)ws_size;
  const float* x  = (const float*)d_in[0];
  const float* Wq = (const float*)d_in[1];
  const float* Wk = (const float*)d_in[2];
  const float* Wv = (const float*)d_in[3];
  const float* Wo = (const float*)d_in[4];
  float* out = (float*)d_out;

  char* w = (char*)d_ws;
  unsigned short* vbf = (unsigned short*)w; w += (size_t)2048 * 1024 * 2;
  unsigned short* wqk = (unsigned short*)w; w += (size_t)2048 * 1024 * 2;
  unsigned short* wvb = (unsigned short*)w; w += (size_t)1024 * 1024 * 2;
  unsigned short* wob = (unsigned short*)w; w += (size_t)1024 * 1024 * 2;
  unsigned short* qkb = (unsigned short*)w; w += (size_t)2048 * 2048 * 2;
  unsigned short* vtb = (unsigned short*)w; w += (size_t)1024 * 2048 * 2;
  unsigned short* qb  = (unsigned short*)w; w += (size_t)2048 * 1024 * 2;
  unsigned short* kb  = (unsigned short*)w; w += (size_t)2048 * 1024 * 2;
  unsigned short* aob = (unsigned short*)w; w += (size_t)2048 * 1024 * 2;
  unsigned short* c2  = (unsigned short*)w; w += (size_t)2048 * 1024 * 2;

  prep_logmap<<<2048, 256, 0, stream>>>(x, vbf);
  conv_weights<<<dim3(1024, 4), 256, 0, stream>>>(Wq, Wk, Wv, Wo, wqk, wvb, wob);

  gemm_fused<<<768, 256, 0, stream>>>(vbf, wqk, wvb, qkb, vtb);

  proj_both<<<dim3(8192, 2), 256, 0, stream>>>(qkb, qb, kb);

  attn_mfma<<<512, 256, 0, stream>>>(qb, kb, vtb, aob);

  gemm_wo<<<256, 256, 0, stream>>>(aob, wob, c2);
  expmap_project<<<2048, 256, 0, stream>>>(c2, out);
}

// Round 5
// 96.710 us; speedup vs baseline: 1.3116x; 1.3116x over previous
//
#include <hip/hip_runtime.h>

#define EPSF 1e-6f

typedef __bf16 bf16x8 __attribute__((ext_vector_type(8)));
typedef float f32x4 __attribute__((ext_vector_type(4)));
typedef __attribute__((address_space(3))) unsigned int as3_uint;
typedef __attribute__((address_space(1))) const unsigned int as1_uint;

__device__ __forceinline__ unsigned short f2bf(float f) {
  unsigned int u = __builtin_bit_cast(unsigned int, f);
  u += 0x7fffu + ((u >> 16) & 1u);
  return (unsigned short)(u >> 16);
}
__device__ __forceinline__ float bf2f(unsigned short u) {
  unsigned int v = (unsigned int)u << 16;
  return __builtin_bit_cast(float, v);
}

// ------- fused: log_map(x) -> vbf (blocks 0..2047) | weight conv (blocks 2048..6143) -------
__global__ __launch_bounds__(256) void prep_and_conv(
    const float* __restrict__ x, const float* __restrict__ Wq,
    const float* __restrict__ Wk, const float* __restrict__ Wv,
    const float* __restrict__ Wo, unsigned short* __restrict__ vbf,
    unsigned short* __restrict__ wqk, unsigned short* __restrict__ wvb,
    unsigned short* __restrict__ wob) {
  int bid = blockIdx.x;
  int tid = threadIdx.x;
  if (bid >= 2048) {
    int t = bid - 2048;
    int y = t >> 10;
    const float* src = (y == 0) ? Wq : (y == 1) ? Wk : (y == 2) ? Wv : Wo;
    unsigned short* dst = (y == 0) ? wqk : (y == 1) ? wqk + 1048576
                          : (y == 2) ? wvb : wob;
    int i = (t & 1023) * 256 + tid;
    f32x4 v = ((const f32x4*)src)[i];
    ushort4 o;
    o.x = f2bf(v[0]); o.y = f2bf(v[1]); o.z = f2bf(v[2]); o.w = f2bf(v[3]);
    ((ushort4*)dst)[i] = o;
    return;
  }
  int row = bid;
  const float* xr = x + (size_t)row * 1024;
  float vals[4];
  float ssq = 0.f;
#pragma unroll
  for (int i = 0; i < 4; ++i) {
    int c = tid + i * 256;
    float t = xr[c];
    if (c == 0) {
      vals[i] = 0.f;
    } else {
      t = fminf(fmaxf(t, -8.f), 8.f);
      vals[i] = t;
      ssq += t * t;
    }
  }
#pragma unroll
  for (int off = 32; off; off >>= 1) ssq += __shfl_xor(ssq, off);
  __shared__ float red[4];
  int wv = tid >> 6;
  if ((tid & 63) == 0) red[wv] = ssq;
  __syncthreads();
  ssq = red[0] + red[1] + red[2] + red[3];

  float y0 = sqrtf(1.f + ssq + EPSF);
  float xy = fminf(-y0, -(1.f + EPSF));
  float mxy = fmaxf(-xy, 1.f + EPSF);
  float dd = fmaxf(acoshf(mxy), 0.001f);
  float d0 = y0 + xy;
  float inn = ssq - d0 * d0;
  float dn = sqrtf(fmaxf(inn, EPSF));
  float inv = dd / (dn + EPSF);

  unsigned short* vr = vbf + (size_t)row * 1024;
#pragma unroll
  for (int i = 0; i < 4; ++i) {
    int c = tid + i * 256;
    float o = (c == 0) ? d0 * inv : vals[i] * inv;
    vr[c] = f2bf(o);
  }
}

// ---------------- shared GEMM body: C[row0.., col0..] (BM=128 BN=64 BK=64) ----------------
__device__ __forceinline__ void gemm_body(
    const unsigned short* __restrict__ A, const unsigned short* __restrict__ Bw,
    unsigned short* __restrict__ C, int N, int K, int row0, int col0,
    unsigned short* As, unsigned short* Bs) {
  int tid = threadIdx.x;
  int lane = tid & 63, w = tid >> 6;
  int wm = (w & 1) * 64, wn = (w >> 1) * 32;
  int lq = lane & 15, g = lane >> 4;
  f32x4 acc[4][2] = {};

  const unsigned short* Ag =
      A + (size_t)(row0 + w * 8 + (lane >> 3)) * K + (lane & 7) * 8;
  const unsigned short* Bg =
      Bw + (size_t)(col0 + w * 8 + (lane >> 3)) * K + (lane & 7) * 8;

  for (int k0 = 0; k0 < K; k0 += 64) {
    __syncthreads();
#pragma unroll
    for (int it = 0; it < 4; ++it)
      __builtin_amdgcn_global_load_lds(
          (as1_uint*)(Ag + (size_t)(it * 32) * K + k0),
          (as3_uint*)&As[(it * 32 + w * 8) * 64], 16, 0, 0);
#pragma unroll
    for (int it = 0; it < 2; ++it)
      __builtin_amdgcn_global_load_lds(
          (as1_uint*)(Bg + (size_t)(it * 32) * K + k0),
          (as3_uint*)&Bs[(it * 32 + w * 8) * 64], 16, 0, 0);
    __syncthreads();
#pragma unroll
    for (int ks = 0; ks < 2; ++ks) {
      bf16x8 af[4], bfr[2];
#pragma unroll
      for (int i = 0; i < 4; ++i)
        af[i] = *(const bf16x8*)&As[(wm + i * 16 + lq) * 64 + ks * 32 + g * 8];
#pragma unroll
      for (int j = 0; j < 2; ++j)
        bfr[j] = *(const bf16x8*)&Bs[(wn + j * 16 + lq) * 64 + ks * 32 + g * 8];
#pragma unroll
      for (int i = 0; i < 4; ++i)
#pragma unroll
        for (int j = 0; j < 2; ++j)
          acc[i][j] =
              __builtin_amdgcn_mfma_f32_16x16x32_bf16(af[i], bfr[j], acc[i][j], 0, 0, 0);
    }
  }
#pragma unroll
  for (int i = 0; i < 4; ++i)
#pragma unroll
    for (int j = 0; j < 2; ++j)
#pragma unroll
      for (int r = 0; r < 4; ++r)
        C[(size_t)(row0 + wm + i * 16 + g * 4 + r) * N + col0 + wn + j * 16 + lq] =
            f2bf(acc[i][j][r]);
}

// QK gemm (blocks 0..511) + Vt gemm (blocks 512..767) fused in one dispatch.
__global__ __launch_bounds__(256) void gemm_fused(
    const unsigned short* __restrict__ vbf, const unsigned short* __restrict__ wqk,
    const unsigned short* __restrict__ wvb, unsigned short* __restrict__ qkb,
    unsigned short* __restrict__ vtb) {
  __shared__ unsigned short As[128 * 64];
  __shared__ unsigned short Bs[64 * 64];
  int bid = blockIdx.x;
  if (bid < 512) {
    gemm_body(vbf, wqk, qkb, 2048, 1024, (bid & 15) * 128, (bid >> 4) * 64, As, Bs);
  } else {
    int t = bid - 512;
    gemm_body(wvb, vbf, vtb, 2048, 1024, (t & 7) * 128, (t >> 3) * 64, As, Bs);
  }
}

// Wo gemm: [2048,1024] @ Wo^T -> [2048,1024]
__global__ __launch_bounds__(256) void gemm_wo(
    const unsigned short* __restrict__ A, const unsigned short* __restrict__ Bw,
    unsigned short* __restrict__ C) {
  __shared__ unsigned short As[128 * 64];
  __shared__ unsigned short Bs[64 * 64];
  gemm_body(A, Bw, C, 1024, 1024, (blockIdx.x & 15) * 128, (blockIdx.x >> 4) * 64,
            As, Bs);
}

// ---------------- per-head projection for q AND k in one dispatch ----------------
__global__ __launch_bounds__(256) void proj_both(
    const unsigned short* __restrict__ qkb, unsigned short* __restrict__ qb,
    unsigned short* __restrict__ kb) {
  int tid = threadIdx.x;
  int qmode = (blockIdx.y == 0);
  int g = blockIdx.x * 4 + (tid >> 6);
  int lane = tid & 63;
  int row = g >> 4, head = g & 15;
  const unsigned short* src = qkb + (qmode ? 0 : 1024);
  unsigned short* dst = qmode ? qb : kb;
  float t = bf2f(src[(size_t)row * 2048 + head * 64 + lane]);
  float sp = fminf(fmaxf(t, -5.f), 5.f);
  float ssq = (lane == 0) ? 0.f : sp * sp;
#pragma unroll
  for (int o = 32; o; o >>= 1) ssq += __shfl_xor(ssq, o);
  float x0 = sqrtf(1.f + ssq + EPSF);
  float o = (lane == 0) ? (qmode ? -x0 : x0) : sp;
  if (qmode) o *= 0.125f;
  dst[(size_t)row * 1024 + head * 64 + lane] = f2bf(o);
}

// ---- MFMA flash attention, KVBLK=64, gload_lds double-buffer (T3 2-phase) ----
// Swizzled LDS achieved via pre-swizzled GLOBAL source + swizzled read (m173):
// LDS slot s of row r holds global col-group s^(r&7).
__global__ __launch_bounds__(256) void attn_mfma(
    const unsigned short* __restrict__ Qb, const unsigned short* __restrict__ Kb,
    const unsigned short* __restrict__ Vtb, unsigned short* __restrict__ Obf) {
  __shared__ unsigned short Ks[2][64 * 64];
  __shared__ unsigned short Vs[2][64 * 64];
  __shared__ unsigned short Ps[4 * 16 * 64];
  int tid = threadIdx.x;
  int lane = tid & 63, w = tid >> 6;
  int g = lane >> 4, lq = lane & 15;
  int bh = blockIdx.x >> 4, qt = blockIdx.x & 15;
  int b = bh >> 4, h = bh & 15;

  const unsigned short* qrow =
      Qb + (size_t)(b * 1024 + qt * 64 + w * 16 + lq) * 1024 + h * 64;
  bf16x8 qf0 = *(const bf16x8*)(qrow + g * 8);
  bf16x8 qf1 = *(const bf16x8*)(qrow + 32 + g * 8);

  float mreg = -1e30f, lreg = 0.f;
  f32x4 acc[4] = {};
  unsigned short* Pw = Ps + w * 16 * 64;
  int sx = 8 * (lq & 7);

  const unsigned short* Ksrc = Kb + (size_t)(b * 1024) * 1024 + h * 64;
  const unsigned short* Vsrc = Vtb + (size_t)(h * 64) * 2048 + b * 1024;

  // staging: wave w, lane l covers LDS rows w*8+(l>>3) (+32 per it), slot l&7.
  // global col-group for that slot = (l&7)^(l>>3)   [involution]
  int srow = lane >> 3;
  int scg = (lane & 7) ^ srow;
  const unsigned short* Kp = Ksrc + (size_t)(w * 8 + srow) * 1024 + scg * 8;
  const unsigned short* Vp = Vsrc + (size_t)(w * 8 + srow) * 2048 + scg * 8;

  auto stage = [&](int buf, int kt) {
#pragma unroll
    for (int it = 0; it < 2; ++it) {
      __builtin_amdgcn_global_load_lds(
          (as1_uint*)(Kp + (size_t)(kt * 64 + it * 32) * 1024),
          (as3_uint*)&Ks[buf][(it * 32 + w * 8) * 64], 16, 0, 0);
      __builtin_amdgcn_global_load_lds(
          (as1_uint*)(Vp + (size_t)(it * 32) * 2048 + kt * 64),
          (as3_uint*)&Vs[buf][(it * 32 + w * 8) * 64], 16, 0, 0);
    }
  };

  auto compute = [&](int buf) {
    f32x4 st[4];
#pragma unroll
    for (int i = 0; i < 4; ++i) {
      int ro = i * 16 + lq;
      int rb = ro * 64, xx = 8 * (ro & 7);
      bf16x8 a0 = *(const bf16x8*)&Ks[buf][rb + ((g * 8) ^ xx)];
      bf16x8 a1 = *(const bf16x8*)&Ks[buf][rb + ((32 + g * 8) ^ xx)];
      f32x4 z = {};
      z = __builtin_amdgcn_mfma_f32_16x16x32_bf16(a0, qf0, z, 0, 0, 0);
      st[i] = __builtin_amdgcn_mfma_f32_16x16x32_bf16(a1, qf1, z, 0, 0, 0);
    }
    float pmax = st[0][0];
#pragma unroll
    for (int i = 0; i < 4; ++i)
#pragma unroll
      for (int r = 0; r < 4; ++r) pmax = fmaxf(pmax, st[i][r]);
    pmax = fmaxf(pmax, __shfl_xor(pmax, 16));
    pmax = fmaxf(pmax, __shfl_xor(pmax, 32));
    float nm = fmaxf(mreg, pmax);
    float sc_ = __expf(mreg - nm);
    mreg = nm;
    float ps = 0.f;
#pragma unroll
    for (int i = 0; i < 4; ++i) {
      ushort4 pq;
      float p0 = __expf(st[i][0] - nm);
      float p1 = __expf(st[i][1] - nm);
      float p2 = __expf(st[i][2] - nm);
      float p3 = __expf(st[i][3] - nm);
      ps += (p0 + p1) + (p2 + p3);
      pq.x = f2bf(p0); pq.y = f2bf(p1); pq.z = f2bf(p2); pq.w = f2bf(p3);
      *(ushort4*)&Pw[lq * 64 + ((g * 4 + i * 16) ^ sx)] = pq;
    }
    ps += __shfl_xor(ps, 16);
    ps += __shfl_xor(ps, 32);
    lreg = lreg * sc_ + ps;

    float scr[4];
#pragma unroll
    for (int r = 0; r < 4; ++r) scr[r] = __shfl(sc_, g * 4 + r);
#pragma unroll
    for (int jj = 0; jj < 4; ++jj)
#pragma unroll
      for (int r = 0; r < 4; ++r) acc[jj][r] *= scr[r];
#pragma unroll
    for (int ks = 0; ks < 2; ++ks) {
      bf16x8 pa = *(const bf16x8*)&Pw[lq * 64 + ((ks * 32 + g * 8) ^ sx)];
#pragma unroll
      for (int jj = 0; jj < 4; ++jj) {
        int vr = 16 * jj + lq;
        bf16x8 vb = *(const bf16x8*)&Vs[buf][vr * 64 + ((ks * 32 + g * 8) ^ (8 * (vr & 7)))];
        acc[jj] = __builtin_amdgcn_mfma_f32_16x16x32_bf16(pa, vb, acc[jj], 0, 0, 0);
      }
    }
  };

  stage(0, 0);
  int buf = 0;
  for (int kt = 0; kt < 16; ++kt) {
    __syncthreads();  // drains vmcnt: stage(kt) landed; prior readers of buf^1 done
    if (kt + 1 < 16) stage(buf ^ 1, kt + 1);  // in flight under compute(kt)
    compute(buf);
    buf ^= 1;
  }

  float linv = 1.f / lreg;
  float ilr[4];
#pragma unroll
  for (int r = 0; r < 4; ++r) ilr[r] = __shfl(linv, g * 4 + r);
  unsigned short* obase =
      Obf + (size_t)(b * 1024 + qt * 64 + w * 16) * 1024 + h * 64;
#pragma unroll
  for (int r = 0; r < 4; ++r)
#pragma unroll
    for (int jj = 0; jj < 4; ++jj)
      obase[(size_t)(g * 4 + r) * 1024 + 16 * jj + lq] = f2bf(acc[jj][r] * ilr[r]);
}

// ---------------- exp_map at origin + project (bf16 in, f32 out) ----------------
__global__ __launch_bounds__(256) void expmap_project(
    const unsigned short* __restrict__ c2, float* __restrict__ out) {
  int row = blockIdx.x;
  int tid = threadIdx.x;
  const unsigned short* cr = c2 + (size_t)row * 1024;
  float vals[4];
  float ssq = 0.f;
#pragma unroll
  for (int i = 0; i < 4; ++i) {
    int c = tid + i * 256;
    float t = bf2f(cr[c]);
    vals[i] = (c == 0) ? 0.f : t;
    ssq += vals[i] * vals[i];
  }
#pragma unroll
  for (int off = 32; off; off >>= 1) ssq += __shfl_xor(ssq, off);
  __shared__ float red1[4], red2[4];
  int wv = tid >> 6;
  if ((tid & 63) == 0) red1[wv] = ssq;
  __syncthreads();
  ssq = red1[0] + red1[1] + red1[2] + red1[3];
  float vn = fminf(sqrtf(ssq + EPSF), 5.f);
  float bf = sinhf(vn) / (vn + EPSF);
  float s2 = 0.f;
#pragma unroll
  for (int i = 0; i < 4; ++i) {
    float r = fminf(fmaxf(bf * vals[i], -8.f), 8.f);
    vals[i] = r;
    s2 += r * r;
  }
#pragma unroll
  for (int off = 32; off; off >>= 1) s2 += __shfl_xor(s2, off);
  if ((tid & 63) == 0) red2[wv] = s2;
  __syncthreads();
  s2 = red2[0] + red2[1] + red2[2] + red2[3];
  float x0 = sqrtf(1.f + s2 + EPSF);
  float* orow = out + (size_t)row * 1024;
#pragma unroll
  for (int i = 0; i < 4; ++i) {
    int c = tid + i * 256;
    orow[c] = (c == 0) ? x0 : vals[i];
  }
}

extern "C" void kernel_launch(void* const* d_in, const int* in_sizes, int n_in,
                              void* d_out, int out_size, void* d_ws, size_t ws_size,
                              hipStream_t stream) {
  (void)in_sizes; (void)n_in; (void)out_size; (void)ws_size;
  const float* x  = (const float*)d_in[0];
  const float* Wq = (const float*)d_in[1];
  const float* Wk = (const float*)d_in[2];
  const float* Wv = (const float*)d_in[3];
  const float* Wo = (const float*)d_in[4];
  float* out = (float*)d_out;

  char* w = (char*)d_ws;
  unsigned short* vbf = (unsigned short*)w; w += (size_t)2048 * 1024 * 2;
  unsigned short* wqk = (unsigned short*)w; w += (size_t)2048 * 1024 * 2;
  unsigned short* wvb = (unsigned short*)w; w += (size_t)1024 * 1024 * 2;
  unsigned short* wob = (unsigned short*)w; w += (size_t)1024 * 1024 * 2;
  unsigned short* qkb = (unsigned short*)w; w += (size_t)2048 * 2048 * 2;
  unsigned short* vtb = (unsigned short*)w; w += (size_t)1024 * 2048 * 2;
  unsigned short* qb  = (unsigned short*)w; w += (size_t)2048 * 1024 * 2;
  unsigned short* kb  = (unsigned short*)w; w += (size_t)2048 * 1024 * 2;
  unsigned short* aob = (unsigned short*)w; w += (size_t)2048 * 1024 * 2;
  unsigned short* c2  = (unsigned short*)w; w += (size_t)2048 * 1024 * 2;

  prep_and_conv<<<6144, 256, 0, stream>>>(x, Wq, Wk, Wv, Wo, vbf, wqk, wvb, wob);

  gemm_fused<<<768, 256, 0, stream>>>(vbf, wqk, wvb, qkb, vtb);

  proj_both<<<dim3(8192, 2), 256, 0, stream>>>(qkb, qb, kb);

  attn_mfma<<<512, 256, 0, stream>>>(qb, kb, vtb, aob);

  gemm_wo<<<256, 256, 0, stream>>>(aob, wob, c2);
  expmap_project<<<2048, 256, 0, stream>>>(c2, out);
}

// Round 6
// 93.234 us; speedup vs baseline: 1.3605x; 1.0373x over previous
//
#include <hip/hip_runtime.h>

#define EPSF 1e-6f

typedef __bf16 bf16x8 __attribute__((ext_vector_type(8)));
typedef float f32x4 __attribute__((ext_vector_type(4)));
typedef __attribute__((address_space(3))) unsigned int as3_uint;
typedef __attribute__((address_space(1))) const unsigned int as1_uint;

__device__ __forceinline__ unsigned short f2bf(float f) {
  unsigned int u = __builtin_bit_cast(unsigned int, f);
  u += 0x7fffu + ((u >> 16) & 1u);
  return (unsigned short)(u >> 16);
}
__device__ __forceinline__ float bf2f(unsigned short u) {
  unsigned int v = (unsigned int)u << 16;
  return __builtin_bit_cast(float, v);
}

// ------- fused: log_map(x) -> vbf (blocks 0..2047) | weight conv (blocks 2048..6143) -------
__global__ __launch_bounds__(256) void prep_and_conv(
    const float* __restrict__ x, const float* __restrict__ Wq,
    const float* __restrict__ Wk, const float* __restrict__ Wv,
    const float* __restrict__ Wo, unsigned short* __restrict__ vbf,
    unsigned short* __restrict__ wqk, unsigned short* __restrict__ wvb,
    unsigned short* __restrict__ wob) {
  int bid = blockIdx.x;
  int tid = threadIdx.x;
  if (bid >= 2048) {
    int t = bid - 2048;
    int y = t >> 10;
    const float* src = (y == 0) ? Wq : (y == 1) ? Wk : (y == 2) ? Wv : Wo;
    unsigned short* dst = (y == 0) ? wqk : (y == 1) ? wqk + 1048576
                          : (y == 2) ? wvb : wob;
    int i = (t & 1023) * 256 + tid;
    f32x4 v = ((const f32x4*)src)[i];
    ushort4 o;
    o.x = f2bf(v[0]); o.y = f2bf(v[1]); o.z = f2bf(v[2]); o.w = f2bf(v[3]);
    ((ushort4*)dst)[i] = o;
    return;
  }
  int row = bid;
  const float* xr = x + (size_t)row * 1024;
  float vals[4];
  float ssq = 0.f;
#pragma unroll
  for (int i = 0; i < 4; ++i) {
    int c = tid + i * 256;
    float t = xr[c];
    if (c == 0) {
      vals[i] = 0.f;
    } else {
      t = fminf(fmaxf(t, -8.f), 8.f);
      vals[i] = t;
      ssq += t * t;
    }
  }
#pragma unroll
  for (int off = 32; off; off >>= 1) ssq += __shfl_xor(ssq, off);
  __shared__ float red[4];
  int wv = tid >> 6;
  if ((tid & 63) == 0) red[wv] = ssq;
  __syncthreads();
  ssq = red[0] + red[1] + red[2] + red[3];

  float y0 = sqrtf(1.f + ssq + EPSF);
  float xy = fminf(-y0, -(1.f + EPSF));
  float mxy = fmaxf(-xy, 1.f + EPSF);
  float dd = fmaxf(acoshf(mxy), 0.001f);
  float d0 = y0 + xy;
  float inn = ssq - d0 * d0;
  float dn = sqrtf(fmaxf(inn, EPSF));
  float inv = dd / (dn + EPSF);

  unsigned short* vr = vbf + (size_t)row * 1024;
#pragma unroll
  for (int i = 0; i < 4; ++i) {
    int c = tid + i * 256;
    float o = (c == 0) ? d0 * inv : vals[i] * inv;
    vr[c] = f2bf(o);
  }
}

// ---------- 128x128-tile GEMM body (m97 structure): acc += A[row0..][K] @ B[col0..][K]^T ----
__device__ __forceinline__ void gemm128_body(
    const unsigned short* __restrict__ A, const unsigned short* __restrict__ Bw,
    int K, int row0, int col0, unsigned short* As, unsigned short* Bs,
    f32x4 (*acc)[4]) {
  int tid = threadIdx.x;
  int lane = tid & 63, w = tid >> 6;
  int wm = (w >> 1) * 64, wn = (w & 1) * 64;
  int lq = lane & 15, g = lane >> 4;
  const unsigned short* Ag =
      A + (size_t)(row0 + w * 8 + (lane >> 3)) * K + (lane & 7) * 8;
  const unsigned short* Bg =
      Bw + (size_t)(col0 + w * 8 + (lane >> 3)) * K + (lane & 7) * 8;

  for (int k0 = 0; k0 < K; k0 += 64) {
    __syncthreads();
#pragma unroll
    for (int it = 0; it < 4; ++it) {
      __builtin_amdgcn_global_load_lds(
          (as1_uint*)(Ag + (size_t)(it * 32) * K + k0),
          (as3_uint*)&As[(it * 32 + w * 8) * 64], 16, 0, 0);
      __builtin_amdgcn_global_load_lds(
          (as1_uint*)(Bg + (size_t)(it * 32) * K + k0),
          (as3_uint*)&Bs[(it * 32 + w * 8) * 64], 16, 0, 0);
    }
    __syncthreads();
#pragma unroll
    for (int ks = 0; ks < 2; ++ks) {
      bf16x8 af[4], bfr[4];
#pragma unroll
      for (int i = 0; i < 4; ++i)
        af[i] = *(const bf16x8*)&As[(wm + i * 16 + lq) * 64 + ks * 32 + g * 8];
#pragma unroll
      for (int j = 0; j < 4; ++j)
        bfr[j] = *(const bf16x8*)&Bs[(wn + j * 16 + lq) * 64 + ks * 32 + g * 8];
#pragma unroll
      for (int i = 0; i < 4; ++i)
#pragma unroll
        for (int j = 0; j < 4; ++j)
          acc[i][j] =
              __builtin_amdgcn_mfma_f32_16x16x32_bf16(af[i], bfr[j], acc[i][j], 0, 0, 0);
    }
  }
}

// QK gemm + fused per-head projection (blocks 0..255) | Vt gemm (blocks 256..383)
__global__ __launch_bounds__(256) void gemm_qkv(
    const unsigned short* __restrict__ vbf, const unsigned short* __restrict__ wqk,
    const unsigned short* __restrict__ wvb, unsigned short* __restrict__ qb,
    unsigned short* __restrict__ kb, unsigned short* __restrict__ vtb) {
  __shared__ unsigned short As[128 * 64];
  __shared__ unsigned short Bs[128 * 64];
  f32x4 acc[4][4] = {};
  int tid = threadIdx.x;
  int lane = tid & 63, w = tid >> 6;
  int wm = (w >> 1) * 64, wn = (w & 1) * 64;
  int lq = lane & 15, g = lane >> 4;
  int bid = blockIdx.x;

  if (bid < 256) {
    int row0 = (bid & 15) * 128, col0 = (bid >> 4) * 128;
    gemm128_body(vbf, wqk, 1024, row0, col0, As, Bs, acc);
    // wave's 64-col quadrant == exactly one head (64 cols)
    int headg = (col0 + wn) >> 6;  // 0..31 (0-15 = q heads, 16-31 = k heads)
    int qmode = (headg < 16) ? 1 : 0;
    unsigned short* dst = qmode ? qb : kb;
    size_t colb = (size_t)(headg & 15) * 64;
    float scale = qmode ? 0.125f : 1.f;
#pragma unroll
    for (int i = 0; i < 4; ++i)
#pragma unroll
      for (int r = 0; r < 4; ++r) {
        float s = 0.f;
#pragma unroll
        for (int j = 0; j < 4; ++j) {
          float vc = fminf(fmaxf(acc[i][j][r], -5.f), 5.f);
          s += (j == 0 && lq == 0) ? 0.f : vc * vc;  // exclude head col 0
        }
        s += __shfl_xor(s, 1);
        s += __shfl_xor(s, 2);
        s += __shfl_xor(s, 4);
        s += __shfl_xor(s, 8);
        float x0 = sqrtf(1.f + s + EPSF);
        int row = row0 + wm + i * 16 + g * 4 + r;
#pragma unroll
        for (int j = 0; j < 4; ++j) {
          float vc = fminf(fmaxf(acc[i][j][r], -5.f), 5.f);
          float o = (j == 0 && lq == 0) ? (qmode ? -x0 : x0) : vc;
          dst[(size_t)row * 1024 + colb + j * 16 + lq] = f2bf(o * scale);
        }
      }
  } else {
    int t = bid - 256;
    int row0 = (t & 7) * 128, col0 = (t >> 3) * 128;
    gemm128_body(wvb, vbf, 1024, row0, col0, As, Bs, acc);
#pragma unroll
    for (int i = 0; i < 4; ++i)
#pragma unroll
      for (int j = 0; j < 4; ++j)
#pragma unroll
        for (int r = 0; r < 4; ++r)
          vtb[(size_t)(row0 + wm + i * 16 + g * 4 + r) * 2048 + col0 + wn + j * 16 + lq] =
              f2bf(acc[i][j][r]);
  }
}

// Wo gemm: [2048,1024] @ Wo^T -> [2048,1024] bf16
__global__ __launch_bounds__(256) void gemm_wo(
    const unsigned short* __restrict__ A, const unsigned short* __restrict__ Bw,
    unsigned short* __restrict__ C) {
  __shared__ unsigned short As[128 * 64];
  __shared__ unsigned short Bs[128 * 64];
  f32x4 acc[4][4] = {};
  int bid = blockIdx.x;
  int row0 = (bid & 15) * 128, col0 = (bid >> 4) * 128;
  gemm128_body(A, Bw, 1024, row0, col0, As, Bs, acc);
  int tid = threadIdx.x;
  int lane = tid & 63, w = tid >> 6;
  int wm = (w >> 1) * 64, wn = (w & 1) * 64;
  int lq = lane & 15, g = lane >> 4;
#pragma unroll
  for (int i = 0; i < 4; ++i)
#pragma unroll
    for (int j = 0; j < 4; ++j)
#pragma unroll
      for (int r = 0; r < 4; ++r)
        C[(size_t)(row0 + wm + i * 16 + g * 4 + r) * 1024 + col0 + wn + j * 16 + lq] =
            f2bf(acc[i][j][r]);
}

// ---- MFMA flash attention, KVBLK=64, gload_lds double-buffer (T3 2-phase) ----
__global__ __launch_bounds__(256) void attn_mfma(
    const unsigned short* __restrict__ Qb, const unsigned short* __restrict__ Kb,
    const unsigned short* __restrict__ Vtb, unsigned short* __restrict__ Obf) {
  __shared__ unsigned short Ks[2][64 * 64];
  __shared__ unsigned short Vs[2][64 * 64];
  __shared__ unsigned short Ps[4 * 16 * 64];
  int tid = threadIdx.x;
  int lane = tid & 63, w = tid >> 6;
  int g = lane >> 4, lq = lane & 15;
  int bh = blockIdx.x >> 4, qt = blockIdx.x & 15;
  int b = bh >> 4, h = bh & 15;

  const unsigned short* qrow =
      Qb + (size_t)(b * 1024 + qt * 64 + w * 16 + lq) * 1024 + h * 64;
  bf16x8 qf0 = *(const bf16x8*)(qrow + g * 8);
  bf16x8 qf1 = *(const bf16x8*)(qrow + 32 + g * 8);

  float mreg = -1e30f, lreg = 0.f;
  f32x4 acc[4] = {};
  unsigned short* Pw = Ps + w * 16 * 64;
  int sx = 8 * (lq & 7);

  const unsigned short* Ksrc = Kb + (size_t)(b * 1024) * 1024 + h * 64;
  const unsigned short* Vsrc = Vtb + (size_t)(h * 64) * 2048 + b * 1024;

  int srow = lane >> 3;
  int scg = (lane & 7) ^ srow;  // pre-swizzled global source (involution)
  const unsigned short* Kp = Ksrc + (size_t)(w * 8 + srow) * 1024 + scg * 8;
  const unsigned short* Vp = Vsrc + (size_t)(w * 8 + srow) * 2048 + scg * 8;

  auto stage = [&](int buf, int kt) {
#pragma unroll
    for (int it = 0; it < 2; ++it) {
      __builtin_amdgcn_global_load_lds(
          (as1_uint*)(Kp + (size_t)(kt * 64 + it * 32) * 1024),
          (as3_uint*)&Ks[buf][(it * 32 + w * 8) * 64], 16, 0, 0);
      __builtin_amdgcn_global_load_lds(
          (as1_uint*)(Vp + (size_t)(it * 32) * 2048 + kt * 64),
          (as3_uint*)&Vs[buf][(it * 32 + w * 8) * 64], 16, 0, 0);
    }
  };

  auto compute = [&](int buf) {
    f32x4 st[4];
#pragma unroll
    for (int i = 0; i < 4; ++i) {
      int ro = i * 16 + lq;
      int rb = ro * 64, xx = 8 * (ro & 7);
      bf16x8 a0 = *(const bf16x8*)&Ks[buf][rb + ((g * 8) ^ xx)];
      bf16x8 a1 = *(const bf16x8*)&Ks[buf][rb + ((32 + g * 8) ^ xx)];
      f32x4 z = {};
      z = __builtin_amdgcn_mfma_f32_16x16x32_bf16(a0, qf0, z, 0, 0, 0);
      st[i] = __builtin_amdgcn_mfma_f32_16x16x32_bf16(a1, qf1, z, 0, 0, 0);
    }
    float pmax = st[0][0];
#pragma unroll
    for (int i = 0; i < 4; ++i)
#pragma unroll
      for (int r = 0; r < 4; ++r) pmax = fmaxf(pmax, st[i][r]);
    pmax = fmaxf(pmax, __shfl_xor(pmax, 16));
    pmax = fmaxf(pmax, __shfl_xor(pmax, 32));
    float nm = fmaxf(mreg, pmax);
    float sc_ = __expf(mreg - nm);
    mreg = nm;
    float ps = 0.f;
#pragma unroll
    for (int i = 0; i < 4; ++i) {
      ushort4 pq;
      float p0 = __expf(st[i][0] - nm);
      float p1 = __expf(st[i][1] - nm);
      float p2 = __expf(st[i][2] - nm);
      float p3 = __expf(st[i][3] - nm);
      ps += (p0 + p1) + (p2 + p3);
      pq.x = f2bf(p0); pq.y = f2bf(p1); pq.z = f2bf(p2); pq.w = f2bf(p3);
      *(ushort4*)&Pw[lq * 64 + ((g * 4 + i * 16) ^ sx)] = pq;
    }
    ps += __shfl_xor(ps, 16);
    ps += __shfl_xor(ps, 32);
    lreg = lreg * sc_ + ps;

    float scr[4];
#pragma unroll
    for (int r = 0; r < 4; ++r) scr[r] = __shfl(sc_, g * 4 + r);
#pragma unroll
    for (int jj = 0; jj < 4; ++jj)
#pragma unroll
      for (int r = 0; r < 4; ++r) acc[jj][r] *= scr[r];
#pragma unroll
    for (int ks = 0; ks < 2; ++ks) {
      bf16x8 pa = *(const bf16x8*)&Pw[lq * 64 + ((ks * 32 + g * 8) ^ sx)];
#pragma unroll
      for (int jj = 0; jj < 4; ++jj) {
        int vr = 16 * jj + lq;
        bf16x8 vb = *(const bf16x8*)&Vs[buf][vr * 64 + ((ks * 32 + g * 8) ^ (8 * (vr & 7)))];
        acc[jj] = __builtin_amdgcn_mfma_f32_16x16x32_bf16(pa, vb, acc[jj], 0, 0, 0);
      }
    }
  };

  stage(0, 0);
  int buf = 0;
  for (int kt = 0; kt < 16; ++kt) {
    __syncthreads();
    if (kt + 1 < 16) stage(buf ^ 1, kt + 1);
    compute(buf);
    buf ^= 1;
  }

  float linv = 1.f / lreg;
  float ilr[4];
#pragma unroll
  for (int r = 0; r < 4; ++r) ilr[r] = __shfl(linv, g * 4 + r);
  unsigned short* obase =
      Obf + (size_t)(b * 1024 + qt * 64 + w * 16) * 1024 + h * 64;
#pragma unroll
  for (int r = 0; r < 4; ++r)
#pragma unroll
    for (int jj = 0; jj < 4; ++jj)
      obase[(size_t)(g * 4 + r) * 1024 + 16 * jj + lq] = f2bf(acc[jj][r] * ilr[r]);
}

// ---------------- exp_map at origin + project (bf16 in, f32 out) ----------------
__global__ __launch_bounds__(256) void expmap_project(
    const unsigned short* __restrict__ c2, float* __restrict__ out) {
  int row = blockIdx.x;
  int tid = threadIdx.x;
  const unsigned short* cr = c2 + (size_t)row * 1024;
  float vals[4];
  float ssq = 0.f;
#pragma unroll
  for (int i = 0; i < 4; ++i) {
    int c = tid + i * 256;
    float t = bf2f(cr[c]);
    vals[i] = (c == 0) ? 0.f : t;
    ssq += vals[i] * vals[i];
  }
#pragma unroll
  for (int off = 32; off; off >>= 1) ssq += __shfl_xor(ssq, off);
  __shared__ float red1[4], red2[4];
  int wv = tid >> 6;
  if ((tid & 63) == 0) red1[wv] = ssq;
  __syncthreads();
  ssq = red1[0] + red1[1] + red1[2] + red1[3];
  float vn = fminf(sqrtf(ssq + EPSF), 5.f);
  float bf = sinhf(vn) / (vn + EPSF);
  float s2 = 0.f;
#pragma unroll
  for (int i = 0; i < 4; ++i) {
    float r = fminf(fmaxf(bf * vals[i], -8.f), 8.f);
    vals[i] = r;
    s2 += r * r;
  }
#pragma unroll
  for (int off = 32; off; off >>= 1) s2 += __shfl_xor(s2, off);
  if ((tid & 63) == 0) red2[wv] = s2;
  __syncthreads();
  s2 = red2[0] + red2[1] + red2[2] + red2[3];
  float x0 = sqrtf(1.f + s2 + EPSF);
  float* orow = out + (size_t)row * 1024;
#pragma unroll
  for (int i = 0; i < 4; ++i) {
    int c = tid + i * 256;
    orow[c] = (c == 0) ? x0 : vals[i];
  }
}

extern "C" void kernel_launch(void* const* d_in, const int* in_sizes, int n_in,
                              void* d_out, int out_size, void* d_ws, size_t ws_size,
                              hipStream_t stream) {
  (void)in_sizes; (void)n_in; (void)out_size; (void)ws_size;
  const float* x  = (const float*)d_in[0];
  const float* Wq = (const float*)d_in[1];
  const float* Wk = (const float*)d_in[2];
  const float* Wv = (const float*)d_in[3];
  const float* Wo = (const float*)d_in[4];
  float* out = (float*)d_out;

  char* w = (char*)d_ws;
  unsigned short* vbf = (unsigned short*)w; w += (size_t)2048 * 1024 * 2;
  unsigned short* wqk = (unsigned short*)w; w += (size_t)2048 * 1024 * 2;
  unsigned short* wvb = (unsigned short*)w; w += (size_t)1024 * 1024 * 2;
  unsigned short* wob = (unsigned short*)w; w += (size_t)1024 * 1024 * 2;
  unsigned short* vtb = (unsigned short*)w; w += (size_t)1024 * 2048 * 2;
  unsigned short* qb  = (unsigned short*)w; w += (size_t)2048 * 1024 * 2;
  unsigned short* kb  = (unsigned short*)w; w += (size_t)2048 * 1024 * 2;
  unsigned short* aob = (unsigned short*)w; w += (size_t)2048 * 1024 * 2;
  unsigned short* c2  = (unsigned short*)w; w += (size_t)2048 * 1024 * 2;

  prep_and_conv<<<6144, 256, 0, stream>>>(x, Wq, Wk, Wv, Wo, vbf, wqk, wvb, wob);

  gemm_qkv<<<384, 256, 0, stream>>>(vbf, wqk, wvb, qb, kb, vtb);

  attn_mfma<<<512, 256, 0, stream>>>(qb, kb, vtb, aob);

  gemm_wo<<<128, 256, 0, stream>>>(aob, wob, c2);
  expmap_project<<<2048, 256, 0, stream>>>(c2, out);
}

// Round 7
// 84.775 us; speedup vs baseline: 1.4962x; 1.0998x over previous
//
#include <hip/hip_runtime.h>

#define EPSF 1e-6f

typedef __bf16 bf16x8 __attribute__((ext_vector_type(8)));
typedef float f32x4 __attribute__((ext_vector_type(4)));
typedef __attribute__((address_space(3))) unsigned int as3_uint;
typedef __attribute__((address_space(1))) const unsigned int as1_uint;

__device__ __forceinline__ unsigned short f2bf(float f) {
  unsigned int u = __builtin_bit_cast(unsigned int, f);
  u += 0x7fffu + ((u >> 16) & 1u);
  return (unsigned short)(u >> 16);
}
__device__ __forceinline__ float bf2f(unsigned short u) {
  unsigned int v = (unsigned int)u << 16;
  return __builtin_bit_cast(float, v);
}

// ------- fused: log_map(x) -> vbf (blocks 0..2047) | weight conv (blocks 2048..6143) -------
__global__ __launch_bounds__(256) void prep_and_conv(
    const float* __restrict__ x, const float* __restrict__ Wq,
    const float* __restrict__ Wk, const float* __restrict__ Wv,
    const float* __restrict__ Wo, unsigned short* __restrict__ vbf,
    unsigned short* __restrict__ wqk, unsigned short* __restrict__ wvb,
    unsigned short* __restrict__ wob) {
  int bid = blockIdx.x;
  int tid = threadIdx.x;
  if (bid >= 2048) {
    int t = bid - 2048;
    int y = t >> 10;
    const float* src = (y == 0) ? Wq : (y == 1) ? Wk : (y == 2) ? Wv : Wo;
    unsigned short* dst = (y == 0) ? wqk : (y == 1) ? wqk + 1048576
                          : (y == 2) ? wvb : wob;
    int i = (t & 1023) * 256 + tid;
    f32x4 v = ((const f32x4*)src)[i];
    ushort4 o;
    o.x = f2bf(v[0]); o.y = f2bf(v[1]); o.z = f2bf(v[2]); o.w = f2bf(v[3]);
    ((ushort4*)dst)[i] = o;
    return;
  }
  int row = bid;
  const float* xr = x + (size_t)row * 1024;
  float vals[4];
  float ssq = 0.f;
#pragma unroll
  for (int i = 0; i < 4; ++i) {
    int c = tid + i * 256;
    float t = xr[c];
    if (c == 0) {
      vals[i] = 0.f;
    } else {
      t = fminf(fmaxf(t, -8.f), 8.f);
      vals[i] = t;
      ssq += t * t;
    }
  }
#pragma unroll
  for (int off = 32; off; off >>= 1) ssq += __shfl_xor(ssq, off);
  __shared__ float red[4];
  int wv = tid >> 6;
  if ((tid & 63) == 0) red[wv] = ssq;
  __syncthreads();
  ssq = red[0] + red[1] + red[2] + red[3];

  float y0 = sqrtf(1.f + ssq + EPSF);
  float xy = fminf(-y0, -(1.f + EPSF));
  float mxy = fmaxf(-xy, 1.f + EPSF);
  float dd = fmaxf(acoshf(mxy), 0.001f);
  float d0 = y0 + xy;
  float inn = ssq - d0 * d0;
  float dn = sqrtf(fmaxf(inn, EPSF));
  float inv = dd / (dn + EPSF);

  unsigned short* vr = vbf + (size_t)row * 1024;
#pragma unroll
  for (int i = 0; i < 4; ++i) {
    int c = tid + i * 256;
    float o = (c == 0) ? d0 * inv : vals[i] * inv;
    vr[c] = f2bf(o);
  }
}

// ---------- 128x128-tile GEMM body (m97 structure): acc += A[row0..][K] @ B[col0..][K]^T ----
__device__ __forceinline__ void gemm128_body(
    const unsigned short* __restrict__ A, const unsigned short* __restrict__ Bw,
    int K, int row0, int col0, unsigned short* As, unsigned short* Bs,
    f32x4 (*acc)[4]) {
  int tid = threadIdx.x;
  int lane = tid & 63, w = tid >> 6;
  int wm = (w >> 1) * 64, wn = (w & 1) * 64;
  int lq = lane & 15, g = lane >> 4;
  const unsigned short* Ag =
      A + (size_t)(row0 + w * 8 + (lane >> 3)) * K + (lane & 7) * 8;
  const unsigned short* Bg =
      Bw + (size_t)(col0 + w * 8 + (lane >> 3)) * K + (lane & 7) * 8;

  for (int k0 = 0; k0 < K; k0 += 64) {
    __syncthreads();
#pragma unroll
    for (int it = 0; it < 4; ++it) {
      __builtin_amdgcn_global_load_lds(
          (as1_uint*)(Ag + (size_t)(it * 32) * K + k0),
          (as3_uint*)&As[(it * 32 + w * 8) * 64], 16, 0, 0);
      __builtin_amdgcn_global_load_lds(
          (as1_uint*)(Bg + (size_t)(it * 32) * K + k0),
          (as3_uint*)&Bs[(it * 32 + w * 8) * 64], 16, 0, 0);
    }
    __syncthreads();
#pragma unroll
    for (int ks = 0; ks < 2; ++ks) {
      bf16x8 af[4], bfr[4];
#pragma unroll
      for (int i = 0; i < 4; ++i)
        af[i] = *(const bf16x8*)&As[(wm + i * 16 + lq) * 64 + ks * 32 + g * 8];
#pragma unroll
      for (int j = 0; j < 4; ++j)
        bfr[j] = *(const bf16x8*)&Bs[(wn + j * 16 + lq) * 64 + ks * 32 + g * 8];
#pragma unroll
      for (int i = 0; i < 4; ++i)
#pragma unroll
        for (int j = 0; j < 4; ++j)
          acc[i][j] =
              __builtin_amdgcn_mfma_f32_16x16x32_bf16(af[i], bfr[j], acc[i][j], 0, 0, 0);
    }
  }
}

// QK gemm + fused per-head projection (blocks 0..255) | Vt gemm (blocks 256..383)
__global__ __launch_bounds__(256) void gemm_qkv(
    const unsigned short* __restrict__ vbf, const unsigned short* __restrict__ wqk,
    const unsigned short* __restrict__ wvb, unsigned short* __restrict__ qb,
    unsigned short* __restrict__ kb, unsigned short* __restrict__ vtb) {
  __shared__ unsigned short As[128 * 64];
  __shared__ unsigned short Bs[128 * 64];
  f32x4 acc[4][4] = {};
  int tid = threadIdx.x;
  int lane = tid & 63, w = tid >> 6;
  int wm = (w >> 1) * 64, wn = (w & 1) * 64;
  int lq = lane & 15, g = lane >> 4;
  int bid = blockIdx.x;

  if (bid < 256) {
    int row0 = (bid & 15) * 128, col0 = (bid >> 4) * 128;
    gemm128_body(vbf, wqk, 1024, row0, col0, As, Bs, acc);
    int headg = (col0 + wn) >> 6;  // 0..31 (0-15 = q heads, 16-31 = k heads)
    int qmode = (headg < 16) ? 1 : 0;
    unsigned short* dst = qmode ? qb : kb;
    size_t colb = (size_t)(headg & 15) * 64;
    float scale = qmode ? 0.125f : 1.f;
#pragma unroll
    for (int i = 0; i < 4; ++i)
#pragma unroll
      for (int r = 0; r < 4; ++r) {
        float s = 0.f;
#pragma unroll
        for (int j = 0; j < 4; ++j) {
          float vc = fminf(fmaxf(acc[i][j][r], -5.f), 5.f);
          s += (j == 0 && lq == 0) ? 0.f : vc * vc;  // exclude head col 0
        }
        s += __shfl_xor(s, 1);
        s += __shfl_xor(s, 2);
        s += __shfl_xor(s, 4);
        s += __shfl_xor(s, 8);
        float x0 = sqrtf(1.f + s + EPSF);
        int row = row0 + wm + i * 16 + g * 4 + r;
#pragma unroll
        for (int j = 0; j < 4; ++j) {
          float vc = fminf(fmaxf(acc[i][j][r], -5.f), 5.f);
          float o = (j == 0 && lq == 0) ? (qmode ? -x0 : x0) : vc;
          dst[(size_t)row * 1024 + colb + j * 16 + lq] = f2bf(o * scale);
        }
      }
  } else {
    int t = bid - 256;
    int row0 = (t & 7) * 128, col0 = (t >> 3) * 128;
    gemm128_body(wvb, vbf, 1024, row0, col0, As, Bs, acc);
#pragma unroll
    for (int i = 0; i < 4; ++i)
#pragma unroll
      for (int j = 0; j < 4; ++j)
#pragma unroll
        for (int r = 0; r < 4; ++r)
          vtb[(size_t)(row0 + wm + i * 16 + g * 4 + r) * 2048 + col0 + wn + j * 16 + lq] =
              f2bf(acc[i][j][r]);
  }
}

// Wo gemm: BM=128 BN=64 -> 256 blocks (1/CU; was 128 blocks at 128x128)
__global__ __launch_bounds__(256) void gemm_wo(
    const unsigned short* __restrict__ A, const unsigned short* __restrict__ Bw,
    unsigned short* __restrict__ C) {
  __shared__ unsigned short As[128 * 64];
  __shared__ unsigned short Bs[64 * 64];
  int tid = threadIdx.x;
  int lane = tid & 63, w = tid >> 6;
  int wm = (w >> 1) * 64, wn = (w & 1) * 32;
  int lq = lane & 15, g = lane >> 4;
  int row0 = (blockIdx.x & 15) * 128, col0 = (blockIdx.x >> 4) * 64;
  f32x4 acc[4][2] = {};
  const unsigned short* Ag =
      A + (size_t)(row0 + w * 8 + (lane >> 3)) * 1024 + (lane & 7) * 8;
  const unsigned short* Bg =
      Bw + (size_t)(col0 + w * 8 + (lane >> 3)) * 1024 + (lane & 7) * 8;

  for (int k0 = 0; k0 < 1024; k0 += 64) {
    __syncthreads();
#pragma unroll
    for (int it = 0; it < 4; ++it)
      __builtin_amdgcn_global_load_lds(
          (as1_uint*)(Ag + (size_t)(it * 32) * 1024 + k0),
          (as3_uint*)&As[(it * 32 + w * 8) * 64], 16, 0, 0);
#pragma unroll
    for (int it = 0; it < 2; ++it)
      __builtin_amdgcn_global_load_lds(
          (as1_uint*)(Bg + (size_t)(it * 32) * 1024 + k0),
          (as3_uint*)&Bs[(it * 32 + w * 8) * 64], 16, 0, 0);
    __syncthreads();
#pragma unroll
    for (int ks = 0; ks < 2; ++ks) {
      bf16x8 af[4], bfr[2];
#pragma unroll
      for (int i = 0; i < 4; ++i)
        af[i] = *(const bf16x8*)&As[(wm + i * 16 + lq) * 64 + ks * 32 + g * 8];
#pragma unroll
      for (int j = 0; j < 2; ++j)
        bfr[j] = *(const bf16x8*)&Bs[(wn + j * 16 + lq) * 64 + ks * 32 + g * 8];
#pragma unroll
      for (int i = 0; i < 4; ++i)
#pragma unroll
        for (int j = 0; j < 2; ++j)
          acc[i][j] =
              __builtin_amdgcn_mfma_f32_16x16x32_bf16(af[i], bfr[j], acc[i][j], 0, 0, 0);
    }
  }
#pragma unroll
  for (int i = 0; i < 4; ++i)
#pragma unroll
    for (int j = 0; j < 2; ++j)
#pragma unroll
      for (int r = 0; r < 4; ++r)
        C[(size_t)(row0 + wm + i * 16 + g * 4 + r) * 1024 + col0 + wn + j * 16 + lq] =
            f2bf(acc[i][j][r]);
}

// ---- MFMA flash attention, KVBLK=64, gload_lds dbuf, XCD-grouped, defer-max, setprio ----
__global__ __launch_bounds__(256) void attn_mfma(
    const unsigned short* __restrict__ Qb, const unsigned short* __restrict__ Kb,
    const unsigned short* __restrict__ Vtb, unsigned short* __restrict__ Obf) {
  __shared__ unsigned short Ks[2][64 * 64];
  __shared__ unsigned short Vs[2][64 * 64];
  __shared__ unsigned short Ps[4 * 16 * 64];
  int tid = threadIdx.x;
  int lane = tid & 63, w = tid >> 6;
  int g = lane >> 4, lq = lane & 15;
  // XCD grouping: all 16 q-tiles of one (b,h) land on one XCD (bid % 8 constant)
  int bid = blockIdx.x;
  int idx = bid >> 3;               // 0..63
  int bh = (bid & 7) * 4 + (idx & 3);
  int qt = idx >> 2;                // 0..15
  int b = bh >> 4, h = bh & 15;

  const unsigned short* qrow =
      Qb + (size_t)(b * 1024 + qt * 64 + w * 16 + lq) * 1024 + h * 64;
  bf16x8 qf0 = *(const bf16x8*)(qrow + g * 8);
  bf16x8 qf1 = *(const bf16x8*)(qrow + 32 + g * 8);

  float mreg = -1e30f, lreg = 0.f;
  f32x4 acc[4] = {};
  unsigned short* Pw = Ps + w * 16 * 64;
  int sx = 8 * (lq & 7);

  const unsigned short* Ksrc = Kb + (size_t)(b * 1024) * 1024 + h * 64;
  const unsigned short* Vsrc = Vtb + (size_t)(h * 64) * 2048 + b * 1024;

  int srow = lane >> 3;
  int scg = (lane & 7) ^ srow;  // pre-swizzled global source (involution)
  const unsigned short* Kp = Ksrc + (size_t)(w * 8 + srow) * 1024 + scg * 8;
  const unsigned short* Vp = Vsrc + (size_t)(w * 8 + srow) * 2048 + scg * 8;

  auto stage = [&](int buf, int kt) {
#pragma unroll
    for (int it = 0; it < 2; ++it) {
      __builtin_amdgcn_global_load_lds(
          (as1_uint*)(Kp + (size_t)(kt * 64 + it * 32) * 1024),
          (as3_uint*)&Ks[buf][(it * 32 + w * 8) * 64], 16, 0, 0);
      __builtin_amdgcn_global_load_lds(
          (as1_uint*)(Vp + (size_t)(it * 32) * 2048 + kt * 64),
          (as3_uint*)&Vs[buf][(it * 32 + w * 8) * 64], 16, 0, 0);
    }
  };

  auto compute = [&](int buf) {
    f32x4 st[4];
    __builtin_amdgcn_s_setprio(1);
#pragma unroll
    for (int i = 0; i < 4; ++i) {
      int ro = i * 16 + lq;
      int rb = ro * 64, xx = 8 * (ro & 7);
      bf16x8 a0 = *(const bf16x8*)&Ks[buf][rb + ((g * 8) ^ xx)];
      bf16x8 a1 = *(const bf16x8*)&Ks[buf][rb + ((32 + g * 8) ^ xx)];
      f32x4 z = {};
      z = __builtin_amdgcn_mfma_f32_16x16x32_bf16(a0, qf0, z, 0, 0, 0);
      st[i] = __builtin_amdgcn_mfma_f32_16x16x32_bf16(a1, qf1, z, 0, 0, 0);
    }
    __builtin_amdgcn_s_setprio(0);
    float pmax = st[0][0];
#pragma unroll
    for (int i = 0; i < 4; ++i)
#pragma unroll
      for (int r = 0; r < 4; ++r) pmax = fmaxf(pmax, st[i][r]);
    pmax = fmaxf(pmax, __shfl_xor(pmax, 16));
    pmax = fmaxf(pmax, __shfl_xor(pmax, 32));
    // T13 defer-max: only rescale when the running max grows by > 8
    if (__any(pmax > mreg + 8.f)) {
      float nm = fmaxf(mreg, pmax);
      float sc_ = __expf(mreg - nm);
      mreg = nm;
      lreg *= sc_;
      float scr[4];
#pragma unroll
      for (int r = 0; r < 4; ++r) scr[r] = __shfl(sc_, g * 4 + r);
#pragma unroll
      for (int jj = 0; jj < 4; ++jj)
#pragma unroll
        for (int r = 0; r < 4; ++r) acc[jj][r] *= scr[r];
    }
    float ps = 0.f;
#pragma unroll
    for (int i = 0; i < 4; ++i) {
      ushort4 pq;
      float p0 = __expf(st[i][0] - mreg);
      float p1 = __expf(st[i][1] - mreg);
      float p2 = __expf(st[i][2] - mreg);
      float p3 = __expf(st[i][3] - mreg);
      ps += (p0 + p1) + (p2 + p3);
      pq.x = f2bf(p0); pq.y = f2bf(p1); pq.z = f2bf(p2); pq.w = f2bf(p3);
      *(ushort4*)&Pw[lq * 64 + ((g * 4 + i * 16) ^ sx)] = pq;
    }
    ps += __shfl_xor(ps, 16);
    ps += __shfl_xor(ps, 32);
    lreg += ps;

    __builtin_amdgcn_s_setprio(1);
#pragma unroll
    for (int ks = 0; ks < 2; ++ks) {
      bf16x8 pa = *(const bf16x8*)&Pw[lq * 64 + ((ks * 32 + g * 8) ^ sx)];
#pragma unroll
      for (int jj = 0; jj < 4; ++jj) {
        int vr = 16 * jj + lq;
        bf16x8 vb = *(const bf16x8*)&Vs[buf][vr * 64 + ((ks * 32 + g * 8) ^ (8 * (vr & 7)))];
        acc[jj] = __builtin_amdgcn_mfma_f32_16x16x32_bf16(pa, vb, acc[jj], 0, 0, 0);
      }
    }
    __builtin_amdgcn_s_setprio(0);
  };

  stage(0, 0);
  int buf = 0;
  for (int kt = 0; kt < 16; ++kt) {
    __syncthreads();
    if (kt + 1 < 16) stage(buf ^ 1, kt + 1);
    compute(buf);
    buf ^= 1;
  }

  float linv = 1.f / lreg;
  float ilr[4];
#pragma unroll
  for (int r = 0; r < 4; ++r) ilr[r] = __shfl(linv, g * 4 + r);
  unsigned short* obase =
      Obf + (size_t)(b * 1024 + qt * 64 + w * 16) * 1024 + h * 64;
#pragma unroll
  for (int r = 0; r < 4; ++r)
#pragma unroll
    for (int jj = 0; jj < 4; ++jj)
      obase[(size_t)(g * 4 + r) * 1024 + 16 * jj + lq] = f2bf(acc[jj][r] * ilr[r]);
}

// ---------------- exp_map at origin + project (bf16 in, f32 out) ----------------
__global__ __launch_bounds__(256) void expmap_project(
    const unsigned short* __restrict__ c2, float* __restrict__ out) {
  int row = blockIdx.x;
  int tid = threadIdx.x;
  const unsigned short* cr = c2 + (size_t)row * 1024;
  float vals[4];
  float ssq = 0.f;
#pragma unroll
  for (int i = 0; i < 4; ++i) {
    int c = tid + i * 256;
    float t = bf2f(cr[c]);
    vals[i] = (c == 0) ? 0.f : t;
    ssq += vals[i] * vals[i];
  }
#pragma unroll
  for (int off = 32; off; off >>= 1) ssq += __shfl_xor(ssq, off);
  __shared__ float red1[4], red2[4];
  int wv = tid >> 6;
  if ((tid & 63) == 0) red1[wv] = ssq;
  __syncthreads();
  ssq = red1[0] + red1[1] + red1[2] + red1[3];
  float vn = fminf(sqrtf(ssq + EPSF), 5.f);
  float bf = sinhf(vn) / (vn + EPSF);
  float s2 = 0.f;
#pragma unroll
  for (int i = 0; i < 4; ++i) {
    float r = fminf(fmaxf(bf * vals[i], -8.f), 8.f);
    vals[i] = r;
    s2 += r * r;
  }
#pragma unroll
  for (int off = 32; off; off >>= 1) s2 += __shfl_xor(s2, off);
  if ((tid & 63) == 0) red2[wv] = s2;
  __syncthreads();
  s2 = red2[0] + red2[1] + red2[2] + red2[3];
  float x0 = sqrtf(1.f + s2 + EPSF);
  float* orow = out + (size_t)row * 1024;
#pragma unroll
  for (int i = 0; i < 4; ++i) {
    int c = tid + i * 256;
    orow[c] = (c == 0) ? x0 : vals[i];
  }
}

extern "C" void kernel_launch(void* const* d_in, const int* in_sizes, int n_in,
                              void* d_out, int out_size, void* d_ws, size_t ws_size,
                              hipStream_t stream) {
  (void)in_sizes; (void)n_in; (void)out_size; (void)ws_size;
  const float* x  = (const float*)d_in[0];
  const float* Wq = (const float*)d_in[1];
  const float* Wk = (const float*)d_in[2];
  const float* Wv = (const float*)d_in[3];
  const float* Wo = (const float*)d_in[4];
  float* out = (float*)d_out;

  char* w = (char*)d_ws;
  unsigned short* vbf = (unsigned short*)w; w += (size_t)2048 * 1024 * 2;
  unsigned short* wqk = (unsigned short*)w; w += (size_t)2048 * 1024 * 2;
  unsigned short* wvb = (unsigned short*)w; w += (size_t)1024 * 1024 * 2;
  unsigned short* wob = (unsigned short*)w; w += (size_t)1024 * 1024 * 2;
  unsigned short* vtb = (unsigned short*)w; w += (size_t)1024 * 2048 * 2;
  unsigned short* qb  = (unsigned short*)w; w += (size_t)2048 * 1024 * 2;
  unsigned short* kb  = (unsigned short*)w; w += (size_t)2048 * 1024 * 2;
  unsigned short* aob = (unsigned short*)w; w += (size_t)2048 * 1024 * 2;
  unsigned short* c2  = (unsigned short*)w; w += (size_t)2048 * 1024 * 2;

  prep_and_conv<<<6144, 256, 0, stream>>>(x, Wq, Wk, Wv, Wo, vbf, wqk, wvb, wob);

  gemm_qkv<<<384, 256, 0, stream>>>(vbf, wqk, wvb, qb, kb, vtb);

  attn_mfma<<<512, 256, 0, stream>>>(qb, kb, vtb, aob);

  gemm_wo<<<256, 256, 0, stream>>>(aob, wob, c2);
  expmap_project<<<2048, 256, 0, stream>>>(c2, out);
}

// Round 8
// 84.200 us; speedup vs baseline: 1.5064x; 1.0068x over previous
//
#include <hip/hip_runtime.h>

#define EPSF 1e-6f

typedef __bf16 bf16x8 __attribute__((ext_vector_type(8)));
typedef float f32x4 __attribute__((ext_vector_type(4)));
typedef __attribute__((address_space(3))) unsigned int as3_uint;
typedef __attribute__((address_space(1))) const unsigned int as1_uint;

__device__ __forceinline__ unsigned short f2bf(float f) {
  unsigned int u = __builtin_bit_cast(unsigned int, f);
  u += 0x7fffu + ((u >> 16) & 1u);
  return (unsigned short)(u >> 16);
}
__device__ __forceinline__ float bf2f(unsigned short u) {
  unsigned int v = (unsigned int)u << 16;
  return __builtin_bit_cast(float, v);
}

// ------- fused: log_map(x) -> vbf (blocks 0..2047) | weight conv (blocks 2048..6143) -------
__global__ __launch_bounds__(256) void prep_and_conv(
    const float* __restrict__ x, const float* __restrict__ Wq,
    const float* __restrict__ Wk, const float* __restrict__ Wv,
    const float* __restrict__ Wo, unsigned short* __restrict__ vbf,
    unsigned short* __restrict__ wqk, unsigned short* __restrict__ wvb,
    unsigned short* __restrict__ wob) {
  int bid = blockIdx.x;
  int tid = threadIdx.x;
  if (bid >= 2048) {
    int t = bid - 2048;
    int y = t >> 10;
    const float* src = (y == 0) ? Wq : (y == 1) ? Wk : (y == 2) ? Wv : Wo;
    unsigned short* dst = (y == 0) ? wqk : (y == 1) ? wqk + 1048576
                          : (y == 2) ? wvb : wob;
    int i = (t & 1023) * 256 + tid;
    f32x4 v = ((const f32x4*)src)[i];
    ushort4 o;
    o.x = f2bf(v[0]); o.y = f2bf(v[1]); o.z = f2bf(v[2]); o.w = f2bf(v[3]);
    ((ushort4*)dst)[i] = o;
    return;
  }
  int row = bid;
  const float* xr = x + (size_t)row * 1024;
  float vals[4];
  float ssq = 0.f;
#pragma unroll
  for (int i = 0; i < 4; ++i) {
    int c = tid + i * 256;
    float t = xr[c];
    if (c == 0) {
      vals[i] = 0.f;
    } else {
      t = fminf(fmaxf(t, -8.f), 8.f);
      vals[i] = t;
      ssq += t * t;
    }
  }
#pragma unroll
  for (int off = 32; off; off >>= 1) ssq += __shfl_xor(ssq, off);
  __shared__ float red[4];
  int wv = tid >> 6;
  if ((tid & 63) == 0) red[wv] = ssq;
  __syncthreads();
  ssq = red[0] + red[1] + red[2] + red[3];

  float y0 = sqrtf(1.f + ssq + EPSF);
  float xy = fminf(-y0, -(1.f + EPSF));
  float mxy = fmaxf(-xy, 1.f + EPSF);
  float dd = fmaxf(acoshf(mxy), 0.001f);
  float d0 = y0 + xy;
  float inn = ssq - d0 * d0;
  float dn = sqrtf(fmaxf(inn, EPSF));
  float inv = dd / (dn + EPSF);

  unsigned short* vr = vbf + (size_t)row * 1024;
#pragma unroll
  for (int i = 0; i < 4; ++i) {
    int c = tid + i * 256;
    float o = (c == 0) ? d0 * inv : vals[i] * inv;
    vr[c] = f2bf(o);
  }
}

// ---------- 128x128-tile GEMM body, T3 double-buffered LDS staging ----------
// As, Bs each hold 2 x 128x64 bf16 tiles (16 KB per buffer).
__device__ __forceinline__ void gemm128_dbuf(
    const unsigned short* __restrict__ A, const unsigned short* __restrict__ Bw,
    int K, int row0, int col0, unsigned short* As, unsigned short* Bs,
    f32x4 (*acc)[4]) {
  int tid = threadIdx.x;
  int lane = tid & 63, w = tid >> 6;
  int wm = (w >> 1) * 64, wn = (w & 1) * 64;
  int lq = lane & 15, g = lane >> 4;
  const unsigned short* Ag =
      A + (size_t)(row0 + w * 8 + (lane >> 3)) * K + (lane & 7) * 8;
  const unsigned short* Bg =
      Bw + (size_t)(col0 + w * 8 + (lane >> 3)) * K + (lane & 7) * 8;

  auto stage = [&](int buf, int k0) {
#pragma unroll
    for (int it = 0; it < 4; ++it) {
      __builtin_amdgcn_global_load_lds(
          (as1_uint*)(Ag + (size_t)(it * 32) * K + k0),
          (as3_uint*)&As[buf * 8192 + (it * 32 + w * 8) * 64], 16, 0, 0);
      __builtin_amdgcn_global_load_lds(
          (as1_uint*)(Bg + (size_t)(it * 32) * K + k0),
          (as3_uint*)&Bs[buf * 8192 + (it * 32 + w * 8) * 64], 16, 0, 0);
    }
  };

  stage(0, 0);
  int buf = 0;
  for (int k0 = 0; k0 < K; k0 += 64) {
    __syncthreads();  // drains stage(buf); prior readers of buf^1 are done
    if (k0 + 64 < K) stage(buf ^ 1, k0 + 64);  // in flight under compute(buf)
#pragma unroll
    for (int ks = 0; ks < 2; ++ks) {
      bf16x8 af[4], bfr[4];
#pragma unroll
      for (int i = 0; i < 4; ++i)
        af[i] = *(const bf16x8*)&As[buf * 8192 + (wm + i * 16 + lq) * 64 + ks * 32 + g * 8];
#pragma unroll
      for (int j = 0; j < 4; ++j)
        bfr[j] = *(const bf16x8*)&Bs[buf * 8192 + (wn + j * 16 + lq) * 64 + ks * 32 + g * 8];
#pragma unroll
      for (int i = 0; i < 4; ++i)
#pragma unroll
        for (int j = 0; j < 4; ++j)
          acc[i][j] =
              __builtin_amdgcn_mfma_f32_16x16x32_bf16(af[i], bfr[j], acc[i][j], 0, 0, 0);
    }
    buf ^= 1;
  }
}

// QK gemm (256 tiles) + Vt gemm (128 tiles), interleaved bid%3==2 -> Vt for balance
__global__ __launch_bounds__(256) void gemm_qkv(
    const unsigned short* __restrict__ vbf, const unsigned short* __restrict__ wqk,
    const unsigned short* __restrict__ wvb, unsigned short* __restrict__ qb,
    unsigned short* __restrict__ kb, unsigned short* __restrict__ vtb) {
  __shared__ unsigned short As[2 * 8192];
  __shared__ unsigned short Bs[2 * 8192];
  f32x4 acc[4][4] = {};
  int tid = threadIdx.x;
  int lane = tid & 63, w = tid >> 6;
  int wm = (w >> 1) * 64, wn = (w & 1) * 64;
  int lq = lane & 15, g = lane >> 4;
  int bid = blockIdx.x;
  bool isVt = (bid % 3 == 2);

  if (!isVt) {
    int q = bid - (bid + 1) / 3;  // 0..255
    int row0 = (q & 15) * 128, col0 = (q >> 4) * 128;
    gemm128_dbuf(vbf, wqk, 1024, row0, col0, As, Bs, acc);
    int headg = (col0 + wn) >> 6;  // 0..31 (0-15 q heads, 16-31 k heads)
    int qmode = (headg < 16) ? 1 : 0;
    unsigned short* dst = qmode ? qb : kb;
    size_t colb = (size_t)(headg & 15) * 64;
    float scale = qmode ? 0.125f : 1.f;
#pragma unroll
    for (int i = 0; i < 4; ++i)
#pragma unroll
      for (int r = 0; r < 4; ++r) {
        float s = 0.f;
#pragma unroll
        for (int j = 0; j < 4; ++j) {
          float vc = fminf(fmaxf(acc[i][j][r], -5.f), 5.f);
          s += (j == 0 && lq == 0) ? 0.f : vc * vc;  // exclude head col 0
        }
        s += __shfl_xor(s, 1);
        s += __shfl_xor(s, 2);
        s += __shfl_xor(s, 4);
        s += __shfl_xor(s, 8);
        float x0 = sqrtf(1.f + s + EPSF);
        int row = row0 + wm + i * 16 + g * 4 + r;
#pragma unroll
        for (int j = 0; j < 4; ++j) {
          float vc = fminf(fmaxf(acc[i][j][r], -5.f), 5.f);
          float o = (j == 0 && lq == 0) ? (qmode ? -x0 : x0) : vc;
          dst[(size_t)row * 1024 + colb + j * 16 + lq] = f2bf(o * scale);
        }
      }
  } else {
    int t = bid / 3;  // 0..127
    int row0 = (t & 7) * 128, col0 = (t >> 3) * 128;
    gemm128_dbuf(wvb, vbf, 1024, row0, col0, As, Bs, acc);
#pragma unroll
    for (int i = 0; i < 4; ++i)
#pragma unroll
      for (int j = 0; j < 4; ++j)
#pragma unroll
        for (int r = 0; r < 4; ++r)
          vtb[(size_t)(row0 + wm + i * 16 + g * 4 + r) * 2048 + col0 + wn + j * 16 + lq] =
              f2bf(acc[i][j][r]);
  }
}

// Wo gemm: BM=128 BN=64, dbuf staging; 256 blocks
__global__ __launch_bounds__(256) void gemm_wo(
    const unsigned short* __restrict__ A, const unsigned short* __restrict__ Bw,
    unsigned short* __restrict__ C) {
  __shared__ unsigned short As[2 * 8192];
  __shared__ unsigned short Bs[2 * 4096];
  int tid = threadIdx.x;
  int lane = tid & 63, w = tid >> 6;
  int wm = (w >> 1) * 64, wn = (w & 1) * 32;
  int lq = lane & 15, g = lane >> 4;
  int row0 = (blockIdx.x & 15) * 128, col0 = (blockIdx.x >> 4) * 64;
  f32x4 acc[4][2] = {};
  const unsigned short* Ag =
      A + (size_t)(row0 + w * 8 + (lane >> 3)) * 1024 + (lane & 7) * 8;
  const unsigned short* Bg =
      Bw + (size_t)(col0 + w * 8 + (lane >> 3)) * 1024 + (lane & 7) * 8;

  auto stage = [&](int buf, int k0) {
#pragma unroll
    for (int it = 0; it < 4; ++it)
      __builtin_amdgcn_global_load_lds(
          (as1_uint*)(Ag + (size_t)(it * 32) * 1024 + k0),
          (as3_uint*)&As[buf * 8192 + (it * 32 + w * 8) * 64], 16, 0, 0);
#pragma unroll
    for (int it = 0; it < 2; ++it)
      __builtin_amdgcn_global_load_lds(
          (as1_uint*)(Bg + (size_t)(it * 32) * 1024 + k0),
          (as3_uint*)&Bs[buf * 4096 + (it * 32 + w * 8) * 64], 16, 0, 0);
  };

  stage(0, 0);
  int buf = 0;
  for (int k0 = 0; k0 < 1024; k0 += 64) {
    __syncthreads();
    if (k0 + 64 < 1024) stage(buf ^ 1, k0 + 64);
#pragma unroll
    for (int ks = 0; ks < 2; ++ks) {
      bf16x8 af[4], bfr[2];
#pragma unroll
      for (int i = 0; i < 4; ++i)
        af[i] = *(const bf16x8*)&As[buf * 8192 + (wm + i * 16 + lq) * 64 + ks * 32 + g * 8];
#pragma unroll
      for (int j = 0; j < 2; ++j)
        bfr[j] = *(const bf16x8*)&Bs[buf * 4096 + (wn + j * 16 + lq) * 64 + ks * 32 + g * 8];
#pragma unroll
      for (int i = 0; i < 4; ++i)
#pragma unroll
        for (int j = 0; j < 2; ++j)
          acc[i][j] =
              __builtin_amdgcn_mfma_f32_16x16x32_bf16(af[i], bfr[j], acc[i][j], 0, 0, 0);
    }
    buf ^= 1;
  }
#pragma unroll
  for (int i = 0; i < 4; ++i)
#pragma unroll
    for (int j = 0; j < 2; ++j)
#pragma unroll
      for (int r = 0; r < 4; ++r)
        C[(size_t)(row0 + wm + i * 16 + g * 4 + r) * 1024 + col0 + wn + j * 16 + lq] =
            f2bf(acc[i][j][r]);
}

// ---- MFMA flash attention, KVBLK=64, gload_lds dbuf, XCD-grouped, defer-max, setprio ----
__global__ __launch_bounds__(256) void attn_mfma(
    const unsigned short* __restrict__ Qb, const unsigned short* __restrict__ Kb,
    const unsigned short* __restrict__ Vtb, unsigned short* __restrict__ Obf) {
  __shared__ unsigned short Ks[2][64 * 64];
  __shared__ unsigned short Vs[2][64 * 64];
  __shared__ unsigned short Ps[4 * 16 * 64];
  int tid = threadIdx.x;
  int lane = tid & 63, w = tid >> 6;
  int g = lane >> 4, lq = lane & 15;
  int bid = blockIdx.x;
  int idx = bid >> 3;               // 0..63
  int bh = (bid & 7) * 4 + (idx & 3);
  int qt = idx >> 2;                // 0..15
  int b = bh >> 4, h = bh & 15;

  const unsigned short* qrow =
      Qb + (size_t)(b * 1024 + qt * 64 + w * 16 + lq) * 1024 + h * 64;
  bf16x8 qf0 = *(const bf16x8*)(qrow + g * 8);
  bf16x8 qf1 = *(const bf16x8*)(qrow + 32 + g * 8);

  float mreg = -1e30f, lreg = 0.f;
  f32x4 acc[4] = {};
  unsigned short* Pw = Ps + w * 16 * 64;
  int sx = 8 * (lq & 7);

  const unsigned short* Ksrc = Kb + (size_t)(b * 1024) * 1024 + h * 64;
  const unsigned short* Vsrc = Vtb + (size_t)(h * 64) * 2048 + b * 1024;

  int srow = lane >> 3;
  int scg = (lane & 7) ^ srow;  // pre-swizzled global source (involution)
  const unsigned short* Kp = Ksrc + (size_t)(w * 8 + srow) * 1024 + scg * 8;
  const unsigned short* Vp = Vsrc + (size_t)(w * 8 + srow) * 2048 + scg * 8;

  auto stage = [&](int buf, int kt) {
#pragma unroll
    for (int it = 0; it < 2; ++it) {
      __builtin_amdgcn_global_load_lds(
          (as1_uint*)(Kp + (size_t)(kt * 64 + it * 32) * 1024),
          (as3_uint*)&Ks[buf][(it * 32 + w * 8) * 64], 16, 0, 0);
      __builtin_amdgcn_global_load_lds(
          (as1_uint*)(Vp + (size_t)(it * 32) * 2048 + kt * 64),
          (as3_uint*)&Vs[buf][(it * 32 + w * 8) * 64], 16, 0, 0);
    }
  };

  auto compute = [&](int buf) {
    f32x4 st[4];
    __builtin_amdgcn_s_setprio(1);
#pragma unroll
    for (int i = 0; i < 4; ++i) {
      int ro = i * 16 + lq;
      int rb = ro * 64, xx = 8 * (ro & 7);
      bf16x8 a0 = *(const bf16x8*)&Ks[buf][rb + ((g * 8) ^ xx)];
      bf16x8 a1 = *(const bf16x8*)&Ks[buf][rb + ((32 + g * 8) ^ xx)];
      f32x4 z = {};
      z = __builtin_amdgcn_mfma_f32_16x16x32_bf16(a0, qf0, z, 0, 0, 0);
      st[i] = __builtin_amdgcn_mfma_f32_16x16x32_bf16(a1, qf1, z, 0, 0, 0);
    }
    __builtin_amdgcn_s_setprio(0);
    float pmax = st[0][0];
#pragma unroll
    for (int i = 0; i < 4; ++i)
#pragma unroll
      for (int r = 0; r < 4; ++r) pmax = fmaxf(pmax, st[i][r]);
    pmax = fmaxf(pmax, __shfl_xor(pmax, 16));
    pmax = fmaxf(pmax, __shfl_xor(pmax, 32));
    if (__any(pmax > mreg + 8.f)) {
      float nm = fmaxf(mreg, pmax);
      float sc_ = __expf(mreg - nm);
      mreg = nm;
      lreg *= sc_;
      float scr[4];
#pragma unroll
      for (int r = 0; r < 4; ++r) scr[r] = __shfl(sc_, g * 4 + r);
#pragma unroll
      for (int jj = 0; jj < 4; ++jj)
#pragma unroll
        for (int r = 0; r < 4; ++r) acc[jj][r] *= scr[r];
    }
    float ps = 0.f;
#pragma unroll
    for (int i = 0; i < 4; ++i) {
      ushort4 pq;
      float p0 = __expf(st[i][0] - mreg);
      float p1 = __expf(st[i][1] - mreg);
      float p2 = __expf(st[i][2] - mreg);
      float p3 = __expf(st[i][3] - mreg);
      ps += (p0 + p1) + (p2 + p3);
      pq.x = f2bf(p0); pq.y = f2bf(p1); pq.z = f2bf(p2); pq.w = f2bf(p3);
      *(ushort4*)&Pw[lq * 64 + ((g * 4 + i * 16) ^ sx)] = pq;
    }
    ps += __shfl_xor(ps, 16);
    ps += __shfl_xor(ps, 32);
    lreg += ps;

    __builtin_amdgcn_s_setprio(1);
#pragma unroll
    for (int ks = 0; ks < 2; ++ks) {
      bf16x8 pa = *(const bf16x8*)&Pw[lq * 64 + ((ks * 32 + g * 8) ^ sx)];
#pragma unroll
      for (int jj = 0; jj < 4; ++jj) {
        int vr = 16 * jj + lq;
        bf16x8 vb = *(const bf16x8*)&Vs[buf][vr * 64 + ((ks * 32 + g * 8) ^ (8 * (vr & 7)))];
        acc[jj] = __builtin_amdgcn_mfma_f32_16x16x32_bf16(pa, vb, acc[jj], 0, 0, 0);
      }
    }
    __builtin_amdgcn_s_setprio(0);
  };

  stage(0, 0);
  int buf = 0;
  for (int kt = 0; kt < 16; ++kt) {
    __syncthreads();
    if (kt + 1 < 16) stage(buf ^ 1, kt + 1);
    compute(buf);
    buf ^= 1;
  }

  float linv = 1.f / lreg;
  float ilr[4];
#pragma unroll
  for (int r = 0; r < 4; ++r) ilr[r] = __shfl(linv, g * 4 + r);
  unsigned short* obase =
      Obf + (size_t)(b * 1024 + qt * 64 + w * 16) * 1024 + h * 64;
#pragma unroll
  for (int r = 0; r < 4; ++r)
#pragma unroll
    for (int jj = 0; jj < 4; ++jj)
      obase[(size_t)(g * 4 + r) * 1024 + 16 * jj + lq] = f2bf(acc[jj][r] * ilr[r]);
}

// ---------------- exp_map at origin + project (bf16 in, f32 out) ----------------
__global__ __launch_bounds__(256) void expmap_project(
    const unsigned short* __restrict__ c2, float* __restrict__ out) {
  int row = blockIdx.x;
  int tid = threadIdx.x;
  const unsigned short* cr = c2 + (size_t)row * 1024;
  float vals[4];
  float ssq = 0.f;
#pragma unroll
  for (int i = 0; i < 4; ++i) {
    int c = tid + i * 256;
    float t = bf2f(cr[c]);
    vals[i] = (c == 0) ? 0.f : t;
    ssq += vals[i] * vals[i];
  }
#pragma unroll
  for (int off = 32; off; off >>= 1) ssq += __shfl_xor(ssq, off);
  __shared__ float red1[4], red2[4];
  int wv = tid >> 6;
  if ((tid & 63) == 0) red1[wv] = ssq;
  __syncthreads();
  ssq = red1[0] + red1[1] + red1[2] + red1[3];
  float vn = fminf(sqrtf(ssq + EPSF), 5.f);
  float bf = sinhf(vn) / (vn + EPSF);
  float s2 = 0.f;
#pragma unroll
  for (int i = 0; i < 4; ++i) {
    float r = fminf(fmaxf(bf * vals[i], -8.f), 8.f);
    vals[i] = r;
    s2 += r * r;
  }
#pragma unroll
  for (int off = 32; off; off >>= 1) s2 += __shfl_xor(s2, off);
  if ((tid & 63) == 0) red2[wv] = s2;
  __syncthreads();
  s2 = red2[0] + red2[1] + red2[2] + red2[3];
  float x0 = sqrtf(1.f + s2 + EPSF);
  float* orow = out + (size_t)row * 1024;
#pragma unroll
  for (int i = 0; i < 4; ++i) {
    int c = tid + i * 256;
    orow[c] = (c == 0) ? x0 : vals[i];
  }
}

extern "C" void kernel_launch(void* const* d_in, const int* in_sizes, int n_in,
                              void* d_out, int out_size, void* d_ws, size_t ws_size,
                              hipStream_t stream) {
  (void)in_sizes; (void)n_in; (void)out_size; (void)ws_size;
  const float* x  = (const float*)d_in[0];
  const float* Wq = (const float*)d_in[1];
  const float* Wk = (const float*)d_in[2];
  const float* Wv = (const float*)d_in[3];
  const float* Wo = (const float*)d_in[4];
  float* out = (float*)d_out;

  char* w = (char*)d_ws;
  unsigned short* vbf = (unsigned short*)w; w += (size_t)2048 * 1024 * 2;
  unsigned short* wqk = (unsigned short*)w; w += (size_t)2048 * 1024 * 2;
  unsigned short* wvb = (unsigned short*)w; w += (size_t)1024 * 1024 * 2;
  unsigned short* wob = (unsigned short*)w; w += (size_t)1024 * 1024 * 2;
  unsigned short* vtb = (unsigned short*)w; w += (size_t)1024 * 2048 * 2;
  unsigned short* qb  = (unsigned short*)w; w += (size_t)2048 * 1024 * 2;
  unsigned short* kb  = (unsigned short*)w; w += (size_t)2048 * 1024 * 2;
  unsigned short* aob = (unsigned short*)w; w += (size_t)2048 * 1024 * 2;
  unsigned short* c2  = (unsigned short*)w; w += (size_t)2048 * 1024 * 2;

  prep_and_conv<<<6144, 256, 0, stream>>>(x, Wq, Wk, Wv, Wo, vbf, wqk, wvb, wob);

  gemm_qkv<<<384, 256, 0, stream>>>(vbf, wqk, wvb, qb, kb, vtb);

  attn_mfma<<<512, 256, 0, stream>>>(qb, kb, vtb, aob);

  gemm_wo<<<256, 256, 0, stream>>>(aob, wob, c2);
  expmap_project<<<2048, 256, 0, stream>>>(c2, out);
}